// Round 4
// baseline (419.103 us; speedup 1.0000x reference)
//
#include <hip/hip_runtime.h>
#include <hip/hip_bf16.h>

// nnvit_82042465288319 on MI355X (gfx950). B=262144 rows; y[5][32]; 2 layers
// (H=8, HD=4); out = y[0] after layer 1. Inputs f32 (dtype probe keeps a bf16
// path for safety).
//
// Round 7 design (persistent blocks + software pipeline):
//  - Diagnosis: per-wave execution was phase-locked: memory burst (10 loads)
//    then pure compute, serialized; barriers + co-launched waves kept phases
//    correlated across waves -> VALUBusy 33% / HBM 20% never overlapping.
//    R5 (VALU diet) and R6 (LDS params) were neutral because T = mem + compute.
//  - Fix: each block loops over 4 groups of 64 rows. Loop top: wait+convert
//    raw x regs (loaded last iteration) -> yd, then immediately issue next
//    group's 8 loads into the same raw buffer; compute overlays the load
//    latency completely. Single raw buffer (in-order issue makes WAR safe),
//    rolled loop (I-cache), LDS params + token conversion amortized 4x.
//  - Keeps: pi-permuted channels (zero shuffles), f32 V used directly from
//    MFMA acc, padded pb rows, log2e-folded softmax, LDS-staged params.
//  - launch_bounds(256,3): VGPR cap 170 (raw buffer stays live in compute).

#define NTOK 5

typedef decltype(__builtin_amdgcn_cvt_pkrtz(0.0f, 0.0f)) half2_t;
using half8_t = __attribute__((ext_vector_type(8))) _Float16;
using f32x4 = __attribute__((ext_vector_type(4))) float;
using f32x2 = __attribute__((ext_vector_type(2))) float;

union H2 { half2_t h; unsigned int u; };
union H8 { half8_t h; uint4 u4; unsigned int u[4]; };

__device__ __forceinline__ half2_t u2h(unsigned int x) { H2 c; c.u = x; return c.h; }
__device__ __forceinline__ unsigned int h2u(half2_t h) { H2 c; c.h = h; return c.u; }
__device__ __forceinline__ unsigned int pk(float a, float b) {
  return h2u(__builtin_amdgcn_cvt_pkrtz(a, b));
}
__device__ __forceinline__ float bf2f(unsigned short u) {
  union { unsigned int u; float f; } c; c.u = ((unsigned int)u) << 16; return c.f;
}
__device__ __forceinline__ half2_t bfpair2h2(unsigned int u) {
  union { unsigned int u; float f; } lo, hi;
  lo.u = u << 16;
  hi.u = u & 0xffff0000u;
  return __builtin_amdgcn_cvt_pkrtz(lo.f, hi.f);  // exact: bf16 fits fp16 range here
}
// round-to-nearest-even f32 pair -> packed bf16 pair
__device__ __forceinline__ unsigned int f2bfpair(float a, float b) {
  unsigned int ua = __float_as_uint(a), ub = __float_as_uint(b);
  ua = (ua + 0x7fffu + ((ua >> 16) & 1u)) >> 16;
  ub = (ub + 0x7fffu + ((ub >> 16) & 1u)) & 0xffff0000u;
  return ua | ub;
}

// dtype probe: low 16 bits of each word form a normal-band bf16 exponent iff bf16
__device__ __forceinline__ int detect_bf16(const unsigned int* __restrict__ p) {
  int cnt = 0;
#pragma unroll
  for (int i = 0; i < 64; ++i) {
    unsigned int e = (p[i] >> 7) & 0xffu;
    cnt += (e >= 96u && e <= 150u) ? 1 : 0;
  }
  return (cnt >= 40) ? 1 : 0;
}

// channel permutation: pi(8q+j) = 4q + (j&3) + (j>=4 ? 16 : 0)
__device__ __forceinline__ int permch(int pos) {
  return 4 * (pos >> 3) + (pos & 3) + ((pos & 4) ? 16 : 0);
}

// ---------------- prep ----------------
// ws: wqkv u32[3072]@0 | wproj u32[1024]@12288 | bqkv f32[192]@16384
//     bproj f32[64]@17152 | pb f32[640]@17408 (layout [l][h][n][8], *log2e)
//     | flag int@19968
__global__ void prep_kernel(const void* __restrict__ xraw,
                            const void* __restrict__ qkv_w, const void* __restrict__ qkv_b,
                            const void* __restrict__ proj_w, const void* __restrict__ proj_b,
                            const void* __restrict__ pos_b,
                            unsigned int* __restrict__ wqkv, unsigned int* __restrict__ wproj,
                            float* __restrict__ bqkv, float* __restrict__ bproj,
                            float* __restrict__ pb, int* __restrict__ flag) {
  const int t = threadIdx.x;  // single block of 256
  const int isbf = detect_bf16((const unsigned int*)xraw);
  if (t == 0) *flag = isbf;
  const float LOG2E = 1.44269504f;
  if (isbf) {
    const unsigned short* qw = (const unsigned short*)qkv_w;
    const unsigned short* qb = (const unsigned short*)qkv_b;
    const unsigned short* pw = (const unsigned short*)proj_w;
    const unsigned short* pbb = (const unsigned short*)proj_b;
    const unsigned short* pp = (const unsigned short*)pos_b;
    for (int i = t; i < 3072; i += 256) {
      const int row = i >> 4, cp = (i & 15) * 2;
      wqkv[i] = h2u(__builtin_amdgcn_cvt_pkrtz(bf2f(qw[row * 32 + permch(cp)]),
                                               bf2f(qw[row * 32 + permch(cp + 1)])));
    }
    for (int i = t; i < 1024; i += 256) {
      const int row = i >> 4, cp = (i & 15) * 2;
      wproj[i] = h2u(__builtin_amdgcn_cvt_pkrtz(bf2f(pw[row * 32 + permch(cp)]),
                                                bf2f(pw[row * 32 + permch(cp + 1)])));
    }
    for (int i = t; i < 192; i += 256) bqkv[i] = bf2f(qb[i]);
    for (int i = t; i < 64; i += 256) bproj[i] = bf2f(pbb[i]);
    for (int i = t; i < 640; i += 256) {
      const int m = i & 7, r = i >> 3;       // r = lh*5 + n, lh in [0,16)
      const int n = r % 5, lh = r / 5;
      pb[i] = (m < 5) ? bf2f(pp[lh * 25 + n * 5 + m]) * LOG2E : 0.0f;
    }
  } else {
    const float* qw = (const float*)qkv_w;
    const float* qb = (const float*)qkv_b;
    const float* pw = (const float*)proj_w;
    const float* pbb = (const float*)proj_b;
    const float* pp = (const float*)pos_b;
    for (int i = t; i < 3072; i += 256) {
      const int row = i >> 4, cp = (i & 15) * 2;
      wqkv[i] = h2u(__builtin_amdgcn_cvt_pkrtz(qw[row * 32 + permch(cp)],
                                               qw[row * 32 + permch(cp + 1)]));
    }
    for (int i = t; i < 1024; i += 256) {
      const int row = i >> 4, cp = (i & 15) * 2;
      wproj[i] = h2u(__builtin_amdgcn_cvt_pkrtz(pw[row * 32 + permch(cp)],
                                                pw[row * 32 + permch(cp + 1)]));
    }
    for (int i = t; i < 192; i += 256) bqkv[i] = qb[i];
    for (int i = t; i < 64; i += 256) bproj[i] = pbb[i];
    for (int i = t; i < 640; i += 256) {
      const int m = i & 7, r = i >> 3;
      const int n = r % 5, lh = r / 5;
      pb[i] = (m < 5) ? pp[lh * 25 + n * 5 + m] * LOG2E : 0.0f;
    }
  }
}

__device__ __forceinline__ half8_t mk8(const unsigned int (&d)[4]) {
  H8 c; c.u[0] = d[0]; c.u[1] = d[1]; c.u[2] = d[2]; c.u[3] = d[3]; return c.h;
}

// LDS weight-frag read: rows padded to 80B (20 u32). lane holds
// W[row][quad*8 .. quad*8+7] (8 fp16 = 16B). Stride 20 words -> 2-way bank
// aliasing across 16 nl lanes (free per m136).
__device__ __forceinline__ half8_t ldsfrag(const unsigned int* lw, int row, int quad) {
  H8 c; c.u4 = *(const uint4*)(lw + row * 20 + quad * 4); return c.h;
}

// per-lane attention for one head. q/k packed fp16 pairs; v raw f32 MFMA acc.
// pbh points at [n][8]-padded, log2e-prescaled rows (in LDS). No max-shift.
template <int NR>
__device__ __forceinline__ void attn_head(const unsigned int (&qd)[NR][2],
                                          const unsigned int (&kd)[NTOK][2],
                                          const f32x4 (&vv)[NTOK],
                                          const float* pbh,
                                          unsigned int (&od)[NR][2]) {
#pragma unroll
  for (int n = 0; n < NR; ++n) {
    const f32x4 pbv = *(const f32x4*)(pbh + n * 8);
    const float pb4 = pbh[n * 8 + 4];
    const float pbm[NTOK] = {pbv[0], pbv[1], pbv[2], pbv[3], pb4};
    const half2_t q0 = u2h(qd[n][0]), q1 = u2h(qd[n][1]);
    float e[NTOK];
#pragma unroll
    for (int m = 0; m < NTOK; ++m) {
      float d = __builtin_amdgcn_fdot2(q0, u2h(kd[m][0]), 0.0f, false);
      d = __builtin_amdgcn_fdot2(q1, u2h(kd[m][1]), d, false);
      // scale = HD^-0.5 * log2(e) = 0.5 * 1.44269504
      e[m] = __builtin_amdgcn_exp2f(fmaf(d, 0.72134752f, pbm[m]));
    }
    const float ssum = ((e[0] + e[1]) + (e[2] + e[3])) + e[4];
    const float r = __builtin_amdgcn_rcpf(ssum);
    f32x2 o01 = {0.0f, 0.0f}, o23 = {0.0f, 0.0f};
#pragma unroll
    for (int m = 0; m < NTOK; ++m) {
      const f32x2 em = {e[m], e[m]};
      const f32x2 vlo = {vv[m][0], vv[m][1]};
      const f32x2 vhi = {vv[m][2], vv[m][3]};
      o01 = __builtin_elementwise_fma(em, vlo, o01);
      o23 = __builtin_elementwise_fma(em, vhi, o23);
    }
    od[n][0] = pk(o01[0] * r, o01[1] * r);
    od[n][1] = pk(o23[0] * r, o23[1] * r);
  }
}

#define NITER 4

// ---------------- main kernel: 1 wave = 16 rows/group, 4 groups pipelined ----------------
__global__ __launch_bounds__(256, 3) void vit_kernel(
    const void* __restrict__ x, const void* __restrict__ token,
    const unsigned int* __restrict__ wqkv, const unsigned int* __restrict__ wproj,
    const float* __restrict__ bqkv, const float* __restrict__ bproj,
    const float* __restrict__ pb, const int* __restrict__ flag,
    void* __restrict__ out) {
  // LDS parameter cache: ~24KB/block.
  __shared__ unsigned int lds_w[256 * 20];  // rows 0..191 qkv, 192..255 proj; 80B rows
  __shared__ float lds_bq[192];
  __shared__ float lds_bp[64];
  __shared__ float lds_pb[640];

  const int tid = threadIdx.x;
  const int wave = tid >> 6, lane = tid & 63;
  const int quad = lane >> 4, nl = lane & 15;
  const int rowoff = wave * 16 + nl;
  const size_t bbase = (size_t)blockIdx.x * (64 * NITER) + rowoff;
  const int isbf = *flag;  // wave-uniform

  // ---- preload group 0 raw x (issued before staging/barrier to hide latency)
  float4 rawf[8];
  uint2 rawb[8];
  if (isbf) {
    const unsigned short* xbp = (const unsigned short*)x + bbase * 128;
#pragma unroll
    for (int t = 1; t < NTOK; ++t) {
      const unsigned short* base = xbp + (t - 1) * 32;
      rawb[2 * (t - 1)] = *(const uint2*)(base + quad * 4);
      rawb[2 * (t - 1) + 1] = *(const uint2*)(base + quad * 4 + 16);
    }
  } else {
    const float* xbp = (const float*)x + bbase * 128;
#pragma unroll
    for (int t = 1; t < NTOK; ++t) {
      const float* base = xbp + (t - 1) * 32;
      rawf[2 * (t - 1)] = *(const float4*)(base + quad * 4);
      rawf[2 * (t - 1) + 1] = *(const float4*)(base + quad * 4 + 16);
    }
  }

  // ---- stage parameters into LDS (global ws is small + L2-hot)
  {
    const uint4* sq = (const uint4*)wqkv;  // 768 uint4
#pragma unroll
    for (int k = 0; k < 3; ++k) {
      const int i = tid + k * 256;
      *(uint4*)(lds_w + (i >> 2) * 20 + (i & 3) * 4) = sq[i];
    }
    const uint4* sp = (const uint4*)wproj;  // 256 uint4
    *(uint4*)(lds_w + (192 + (tid >> 2)) * 20 + (tid & 3) * 4) = sp[tid];
    if (tid < 192) lds_bq[tid] = bqkv[tid];
    if (tid < 64) lds_bp[tid] = bproj[tid];
    {
      const uint4* spb = (const uint4*)pb;  // 160 uint4
      if (tid < 160) *(uint4*)((float*)lds_pb + tid * 4) = spb[tid];
    }
  }

  // ---- token -> fp16 pi layout once (reused every group; yd[0] reset per iter)
  unsigned int tokd[4];
  if (isbf) {
    const unsigned short* tk = (const unsigned short*)token;
    const uint2 t0 = *(const uint2*)(tk + quad * 4);
    const uint2 t1 = *(const uint2*)(tk + quad * 4 + 16);
    tokd[0] = h2u(bfpair2h2(t0.x)); tokd[1] = h2u(bfpair2h2(t0.y));
    tokd[2] = h2u(bfpair2h2(t1.x)); tokd[3] = h2u(bfpair2h2(t1.y));
  } else {
    const float* tk = (const float*)token;
    const float4 a0 = *(const float4*)(tk + quad * 4);
    const float4 a1 = *(const float4*)(tk + quad * 4 + 16);
    tokd[0] = pk(a0.x, a0.y); tokd[1] = pk(a0.z, a0.w);
    tokd[2] = pk(a1.x, a1.y); tokd[3] = pk(a1.z, a1.w);
  }
  __syncthreads();

#pragma unroll 1
  for (int it = 0; it < NITER; ++it) {
    const size_t bcur = bbase + (size_t)it * 64;

    // ---- convert raw -> yd (the only vmcnt wait; loads had a full body to land)
    unsigned int yd[NTOK][4];
    yd[0][0] = tokd[0]; yd[0][1] = tokd[1]; yd[0][2] = tokd[2]; yd[0][3] = tokd[3];
    if (isbf) {
#pragma unroll
      for (int t = 1; t < NTOK; ++t) {
        yd[t][0] = h2u(bfpair2h2(rawb[2 * (t - 1)].x));
        yd[t][1] = h2u(bfpair2h2(rawb[2 * (t - 1)].y));
        yd[t][2] = h2u(bfpair2h2(rawb[2 * (t - 1) + 1].x));
        yd[t][3] = h2u(bfpair2h2(rawb[2 * (t - 1) + 1].y));
      }
    } else {
#pragma unroll
      for (int t = 1; t < NTOK; ++t) {
        yd[t][0] = pk(rawf[2 * (t - 1)].x, rawf[2 * (t - 1)].y);
        yd[t][1] = pk(rawf[2 * (t - 1)].z, rawf[2 * (t - 1)].w);
        yd[t][2] = pk(rawf[2 * (t - 1) + 1].x, rawf[2 * (t - 1) + 1].y);
        yd[t][3] = pk(rawf[2 * (t - 1) + 1].z, rawf[2 * (t - 1) + 1].w);
      }
    }

    // ---- issue next group's loads NOW (hidden under the whole compute body)
    {
      const int itn = (it < NITER - 1) ? it + 1 : it;  // last iter: harmless reload
      const size_t bnext = bbase + (size_t)itn * 64;
      if (isbf) {
        const unsigned short* xbp = (const unsigned short*)x + bnext * 128;
#pragma unroll
        for (int t = 1; t < NTOK; ++t) {
          const unsigned short* base = xbp + (t - 1) * 32;
          rawb[2 * (t - 1)] = *(const uint2*)(base + quad * 4);
          rawb[2 * (t - 1) + 1] = *(const uint2*)(base + quad * 4 + 16);
        }
      } else {
        const float* xbp = (const float*)x + bnext * 128;
#pragma unroll
        for (int t = 1; t < NTOK; ++t) {
          const float* base = xbp + (t - 1) * 32;
          rawf[2 * (t - 1)] = *(const float4*)(base + quad * 4);
          rawf[2 * (t - 1) + 1] = *(const float4*)(base + quad * 4 + 16);
        }
      }
    }

    // ===================== layer 0 =====================
    unsigned int od[2][NTOK][2];
#pragma unroll
    for (int s = 0; s < 2; ++s) {  // head-slot pass: tiles {s,2+s,4+s} = q,k,v of head quad+4s
      const half8_t waq = ldsfrag(lds_w, (s) * 16 + nl, quad);
      const half8_t wak = ldsfrag(lds_w, (2 + s) * 16 + nl, quad);
      const half8_t wav = ldsfrag(lds_w, (4 + s) * 16 + nl, quad);
      const f32x4 bq = *(const f32x4*)(lds_bq + (s) * 16 + quad * 4);
      const f32x4 bk = *(const f32x4*)(lds_bq + (2 + s) * 16 + quad * 4);
      const f32x4 bv = *(const f32x4*)(lds_bq + (4 + s) * 16 + quad * 4);
      unsigned int qd[NTOK][2], kd[NTOK][2];
      f32x4 vv[NTOK];
#pragma unroll
      for (int t = 0; t < NTOK; ++t) {
        const half8_t yb = mk8(yd[t]);
        const f32x4 aq = __builtin_amdgcn_mfma_f32_16x16x32_f16(waq, yb, bq, 0, 0, 0);
        qd[t][0] = pk(aq[0], aq[1]); qd[t][1] = pk(aq[2], aq[3]);
        const f32x4 ak = __builtin_amdgcn_mfma_f32_16x16x32_f16(wak, yb, bk, 0, 0, 0);
        kd[t][0] = pk(ak[0], ak[1]); kd[t][1] = pk(ak[2], ak[3]);
        vv[t] = __builtin_amdgcn_mfma_f32_16x16x32_f16(wav, yb, bv, 0, 0, 0);
      }
      attn_head<NTOK>(qd, kd, vv, lds_pb + (quad + 4 * s) * 40, od[s]);
    }

    {  // proj + residual; o natively pi layout -> direct B-operand; C natively pi
      half8_t wp[2]; f32x4 bp[2];
#pragma unroll
      for (int tile = 0; tile < 2; ++tile) {
        wp[tile] = ldsfrag(lds_w, 192 + tile * 16 + nl, quad);
        bp[tile] = *(const f32x4*)(lds_bp + tile * 16 + quad * 4);
      }
#pragma unroll
      for (int t = 0; t < NTOK; ++t) {
        unsigned int bfr[4] = {od[0][t][0], od[0][t][1], od[1][t][0], od[1][t][1]};
        const half8_t ob = mk8(bfr);
        f32x4 p0 = __builtin_amdgcn_mfma_f32_16x16x32_f16(wp[0], ob, bp[0], 0, 0, 0);
        f32x4 p1 = __builtin_amdgcn_mfma_f32_16x16x32_f16(wp[1], ob, bp[1], 0, 0, 0);
        yd[t][0] = h2u(u2h(yd[t][0]) + u2h(pk(p0[0], p0[1])));
        yd[t][1] = h2u(u2h(yd[t][1]) + u2h(pk(p0[2], p0[3])));
        yd[t][2] = h2u(u2h(yd[t][2]) + u2h(pk(p1[0], p1[1])));
        yd[t][3] = h2u(u2h(yd[t][3]) + u2h(pk(p1[2], p1[3])));
      }
    }

    // ===================== layer 1 (token-0 output only) =====================
    unsigned int o1[2][1][2];
#pragma unroll
    for (int s = 0; s < 2; ++s) {
      const half8_t waq = ldsfrag(lds_w, 96 + (s) * 16 + nl, quad);
      const half8_t wak = ldsfrag(lds_w, 96 + (2 + s) * 16 + nl, quad);
      const half8_t wav = ldsfrag(lds_w, 96 + (4 + s) * 16 + nl, quad);
      const f32x4 bq = *(const f32x4*)(lds_bq + 96 + (s) * 16 + quad * 4);
      const f32x4 bk = *(const f32x4*)(lds_bq + 96 + (2 + s) * 16 + quad * 4);
      const f32x4 bv = *(const f32x4*)(lds_bq + 96 + (4 + s) * 16 + quad * 4);
      unsigned int qd[1][2], kd[NTOK][2];
      f32x4 vv[NTOK];
      {  // q: token 0 only
        const f32x4 aq = __builtin_amdgcn_mfma_f32_16x16x32_f16(waq, mk8(yd[0]), bq, 0, 0, 0);
        qd[0][0] = pk(aq[0], aq[1]); qd[0][1] = pk(aq[2], aq[3]);
      }
#pragma unroll
      for (int t = 0; t < NTOK; ++t) {
        const half8_t yb = mk8(yd[t]);
        const f32x4 ak = __builtin_amdgcn_mfma_f32_16x16x32_f16(wak, yb, bk, 0, 0, 0);
        kd[t][0] = pk(ak[0], ak[1]); kd[t][1] = pk(ak[2], ak[3]);
        vv[t] = __builtin_amdgcn_mfma_f32_16x16x32_f16(wav, yb, bv, 0, 0, 0);
      }
      attn_head<1>(qd, kd, vv, lds_pb + (8 + quad + 4 * s) * 40, o1[s]);
    }

    {
      half8_t wp[2]; f32x4 bp[2];
#pragma unroll
      for (int tile = 0; tile < 2; ++tile) {
        wp[tile] = ldsfrag(lds_w, 192 + 32 + tile * 16 + nl, quad);
        bp[tile] = *(const f32x4*)(lds_bp + 32 + tile * 16 + quad * 4);
      }
      unsigned int bfr[4] = {o1[0][0][0], o1[0][0][1], o1[1][0][0], o1[1][0][1]};
      const half8_t ob = mk8(bfr);
      f32x4 p0 = __builtin_amdgcn_mfma_f32_16x16x32_f16(wp[0], ob, bp[0], 0, 0, 0);
      f32x4 p1 = __builtin_amdgcn_mfma_f32_16x16x32_f16(wp[1], ob, bp[1], 0, 0, 0);

      // f32-exact final residual; lane q holds channels {4q..4q+3, 4q+16..4q+19}
      const half2_t y0 = u2h(yd[0][0]), y1 = u2h(yd[0][1]);
      const half2_t y2 = u2h(yd[0][2]), y3 = u2h(yd[0][3]);
      float f[8] = {(float)y0.x + p0[0], (float)y0.y + p0[1],
                    (float)y1.x + p0[2], (float)y1.y + p0[3],
                    (float)y2.x + p1[0], (float)y2.y + p1[1],
                    (float)y3.x + p1[2], (float)y3.y + p1[3]};
      if (isbf) {
        unsigned short* ob16 = (unsigned short*)out + bcur * 32;
        *(uint2*)(ob16 + quad * 4) = make_uint2(f2bfpair(f[0], f[1]), f2bfpair(f[2], f[3]));
        *(uint2*)(ob16 + quad * 4 + 16) = make_uint2(f2bfpair(f[4], f[5]), f2bfpair(f[6], f[7]));
      } else {
        float* of = (float*)out + bcur * 32;
        *(float4*)(of + quad * 4) = make_float4(f[0], f[1], f[2], f[3]);
        *(float4*)(of + quad * 4 + 16) = make_float4(f[4], f[5], f[6], f[7]);
      }
    }
  }
}

extern "C" void kernel_launch(void* const* d_in, const int* in_sizes, int n_in,
                              void* d_out, int out_size, void* d_ws, size_t ws_size,
                              hipStream_t stream) {
  const void* x      = d_in[0];
  const void* token  = d_in[1];
  const void* qkv_w  = d_in[2];
  const void* qkv_b  = d_in[3];
  const void* proj_w = d_in[4];
  const void* proj_b = d_in[5];
  const void* pos_b  = d_in[6];

  char* ws = (char*)d_ws;
  unsigned int* wqkv  = (unsigned int*)(ws + 0);
  unsigned int* wproj = (unsigned int*)(ws + 12288);
  float* bqkv  = (float*)(ws + 16384);
  float* bproj = (float*)(ws + 17152);
  float* pb    = (float*)(ws + 17408);   // 640 f32, [l][h][n][8] padded
  int*   flag  = (int*)(ws + 19968);

  prep_kernel<<<1, 256, 0, stream>>>(x, qkv_w, qkv_b, proj_w, proj_b, pos_b,
                                     wqkv, wproj, bqkv, bproj, pb, flag);

  const int nrows = in_sizes[0] / 128;   // 262144 batch rows
  const int grid = nrows / (64 * NITER); // 1024 blocks, 4 groups of 64 rows each
  vit_kernel<<<grid, 256, 0, stream>>>(x, token, wqkv, wproj, bqkv, bproj, pb, flag, d_out);
}

// Round 5
// 357.887 us; speedup vs baseline: 1.1710x; 1.1710x over previous
//
#include <hip/hip_runtime.h>
#include <hip/hip_bf16.h>

// nnvit_82042465288319 on MI355X (gfx950). B=262144 rows; y[5][32]; 2 layers
// (H=8, HD=4); out = y[0] after layer 1. Inputs f32 (dtype probe keeps a bf16
// path for safety).
//
// Round 8 design (straight-line 2-deep pipeline; spill-proof R7):
//  - R7's rolled loop demoted loop-carried raw-x arrays to scratch
//    (FETCH/WRITE ~400MB of spill traffic). Same pipeline, straight-line:
//    each wave owns TWO row-groups (b0, b0+64). Issue both groups' x loads
//    up front; g1's loads stay in flight under g0's entire compute.
//  - LDS-staged params are the enabler: group compute has ZERO vmcnt reads
//    (weights/bias/pb on lgkm path), so no intermediate vmcnt wait drains
//    g1's outstanding loads (vmcnt counting is issue-ordered).
//  - All arrays straight-line + constant-indexed (R6-proven promotable).
//    Peak VGPR ~90 < 128 cap at launch_bounds(256,4). Grid = nrows/128.
//  - Keeps: pi-permuted channels (zero shuffles), f32 V direct from MFMA acc,
//    padded pb rows, log2e-folded softmax (no max-shift), LDS params.

#define NTOK 5

typedef decltype(__builtin_amdgcn_cvt_pkrtz(0.0f, 0.0f)) half2_t;
using half8_t = __attribute__((ext_vector_type(8))) _Float16;
using f32x4 = __attribute__((ext_vector_type(4))) float;
using f32x2 = __attribute__((ext_vector_type(2))) float;

union H2 { half2_t h; unsigned int u; };
union H8 { half8_t h; uint4 u4; unsigned int u[4]; };

__device__ __forceinline__ half2_t u2h(unsigned int x) { H2 c; c.u = x; return c.h; }
__device__ __forceinline__ unsigned int h2u(half2_t h) { H2 c; c.h = h; return c.u; }
__device__ __forceinline__ unsigned int pk(float a, float b) {
  return h2u(__builtin_amdgcn_cvt_pkrtz(a, b));
}
__device__ __forceinline__ float bf2f(unsigned short u) {
  union { unsigned int u; float f; } c; c.u = ((unsigned int)u) << 16; return c.f;
}
__device__ __forceinline__ half2_t bfpair2h2(unsigned int u) {
  union { unsigned int u; float f; } lo, hi;
  lo.u = u << 16;
  hi.u = u & 0xffff0000u;
  return __builtin_amdgcn_cvt_pkrtz(lo.f, hi.f);  // exact: bf16 fits fp16 range here
}
// round-to-nearest-even f32 pair -> packed bf16 pair
__device__ __forceinline__ unsigned int f2bfpair(float a, float b) {
  unsigned int ua = __float_as_uint(a), ub = __float_as_uint(b);
  ua = (ua + 0x7fffu + ((ua >> 16) & 1u)) >> 16;
  ub = (ub + 0x7fffu + ((ub >> 16) & 1u)) & 0xffff0000u;
  return ua | ub;
}

// dtype probe: low 16 bits of each word form a normal-band bf16 exponent iff bf16
__device__ __forceinline__ int detect_bf16(const unsigned int* __restrict__ p) {
  int cnt = 0;
#pragma unroll
  for (int i = 0; i < 64; ++i) {
    unsigned int e = (p[i] >> 7) & 0xffu;
    cnt += (e >= 96u && e <= 150u) ? 1 : 0;
  }
  return (cnt >= 40) ? 1 : 0;
}

// channel permutation: pi(8q+j) = 4q + (j&3) + (j>=4 ? 16 : 0)
__device__ __forceinline__ int permch(int pos) {
  return 4 * (pos >> 3) + (pos & 3) + ((pos & 4) ? 16 : 0);
}

// ---------------- prep ----------------
// ws: wqkv u32[3072]@0 | wproj u32[1024]@12288 | bqkv f32[192]@16384
//     bproj f32[64]@17152 | pb f32[640]@17408 (layout [l][h][n][8], *log2e)
//     | flag int@19968
__global__ void prep_kernel(const void* __restrict__ xraw,
                            const void* __restrict__ qkv_w, const void* __restrict__ qkv_b,
                            const void* __restrict__ proj_w, const void* __restrict__ proj_b,
                            const void* __restrict__ pos_b,
                            unsigned int* __restrict__ wqkv, unsigned int* __restrict__ wproj,
                            float* __restrict__ bqkv, float* __restrict__ bproj,
                            float* __restrict__ pb, int* __restrict__ flag) {
  const int t = threadIdx.x;  // single block of 256
  const int isbf = detect_bf16((const unsigned int*)xraw);
  if (t == 0) *flag = isbf;
  const float LOG2E = 1.44269504f;
  if (isbf) {
    const unsigned short* qw = (const unsigned short*)qkv_w;
    const unsigned short* qb = (const unsigned short*)qkv_b;
    const unsigned short* pw = (const unsigned short*)proj_w;
    const unsigned short* pbb = (const unsigned short*)proj_b;
    const unsigned short* pp = (const unsigned short*)pos_b;
    for (int i = t; i < 3072; i += 256) {
      const int row = i >> 4, cp = (i & 15) * 2;
      wqkv[i] = h2u(__builtin_amdgcn_cvt_pkrtz(bf2f(qw[row * 32 + permch(cp)]),
                                               bf2f(qw[row * 32 + permch(cp + 1)])));
    }
    for (int i = t; i < 1024; i += 256) {
      const int row = i >> 4, cp = (i & 15) * 2;
      wproj[i] = h2u(__builtin_amdgcn_cvt_pkrtz(bf2f(pw[row * 32 + permch(cp)]),
                                                bf2f(pw[row * 32 + permch(cp + 1)])));
    }
    for (int i = t; i < 192; i += 256) bqkv[i] = bf2f(qb[i]);
    for (int i = t; i < 64; i += 256) bproj[i] = bf2f(pbb[i]);
    for (int i = t; i < 640; i += 256) {
      const int m = i & 7, r = i >> 3;       // r = lh*5 + n, lh in [0,16)
      const int n = r % 5, lh = r / 5;
      pb[i] = (m < 5) ? bf2f(pp[lh * 25 + n * 5 + m]) * LOG2E : 0.0f;
    }
  } else {
    const float* qw = (const float*)qkv_w;
    const float* qb = (const float*)qkv_b;
    const float* pw = (const float*)proj_w;
    const float* pbb = (const float*)proj_b;
    const float* pp = (const float*)pos_b;
    for (int i = t; i < 3072; i += 256) {
      const int row = i >> 4, cp = (i & 15) * 2;
      wqkv[i] = h2u(__builtin_amdgcn_cvt_pkrtz(qw[row * 32 + permch(cp)],
                                               qw[row * 32 + permch(cp + 1)]));
    }
    for (int i = t; i < 1024; i += 256) {
      const int row = i >> 4, cp = (i & 15) * 2;
      wproj[i] = h2u(__builtin_amdgcn_cvt_pkrtz(pw[row * 32 + permch(cp)],
                                                pw[row * 32 + permch(cp + 1)]));
    }
    for (int i = t; i < 192; i += 256) bqkv[i] = qb[i];
    for (int i = t; i < 64; i += 256) bproj[i] = pbb[i];
    for (int i = t; i < 640; i += 256) {
      const int m = i & 7, r = i >> 3;
      const int n = r % 5, lh = r / 5;
      pb[i] = (m < 5) ? pp[lh * 25 + n * 5 + m] * LOG2E : 0.0f;
    }
  }
}

__device__ __forceinline__ half8_t mk8(const unsigned int (&d)[4]) {
  H8 c; c.u[0] = d[0]; c.u[1] = d[1]; c.u[2] = d[2]; c.u[3] = d[3]; return c.h;
}

// LDS weight-frag read: rows padded to 80B (20 u32). lane holds
// W[row][quad*8 .. quad*8+7] (8 fp16 = 16B). Stride 20 words -> 2-way bank
// aliasing across 16 nl lanes (free per m136).
__device__ __forceinline__ half8_t ldsfrag(const unsigned int* lw, int row, int quad) {
  H8 c; c.u4 = *(const uint4*)(lw + row * 20 + quad * 4); return c.h;
}

// per-lane attention for one head. q/k packed fp16 pairs; v raw f32 MFMA acc.
// pbh points at [n][8]-padded, log2e-prescaled rows (in LDS). No max-shift.
template <int NR>
__device__ __forceinline__ void attn_head(const unsigned int (&qd)[NR][2],
                                          const unsigned int (&kd)[NTOK][2],
                                          const f32x4 (&vv)[NTOK],
                                          const float* pbh,
                                          unsigned int (&od)[NR][2]) {
#pragma unroll
  for (int n = 0; n < NR; ++n) {
    const f32x4 pbv = *(const f32x4*)(pbh + n * 8);
    const float pb4 = pbh[n * 8 + 4];
    const float pbm[NTOK] = {pbv[0], pbv[1], pbv[2], pbv[3], pb4};
    const half2_t q0 = u2h(qd[n][0]), q1 = u2h(qd[n][1]);
    float e[NTOK];
#pragma unroll
    for (int m = 0; m < NTOK; ++m) {
      float d = __builtin_amdgcn_fdot2(q0, u2h(kd[m][0]), 0.0f, false);
      d = __builtin_amdgcn_fdot2(q1, u2h(kd[m][1]), d, false);
      // scale = HD^-0.5 * log2(e) = 0.5 * 1.44269504
      e[m] = __builtin_amdgcn_exp2f(fmaf(d, 0.72134752f, pbm[m]));
    }
    const float ssum = ((e[0] + e[1]) + (e[2] + e[3])) + e[4];
    const float r = __builtin_amdgcn_rcpf(ssum);
    f32x2 o01 = {0.0f, 0.0f}, o23 = {0.0f, 0.0f};
#pragma unroll
    for (int m = 0; m < NTOK; ++m) {
      const f32x2 em = {e[m], e[m]};
      const f32x2 vlo = {vv[m][0], vv[m][1]};
      const f32x2 vhi = {vv[m][2], vv[m][3]};
      o01 = __builtin_elementwise_fma(em, vlo, o01);
      o23 = __builtin_elementwise_fma(em, vhi, o23);
    }
    od[n][0] = pk(o01[0] * r, o01[1] * r);
    od[n][1] = pk(o23[0] * r, o23[1] * r);
  }
}

// Full 2-layer pipeline + store for one 16-row group (per wave). Pure
// LDS/VALU/MFMA - no vmcnt reads inside (keeps other group's x loads in
// flight). yd is consumed/clobbered.
__device__ __forceinline__ void vit_compute_store(
    unsigned int (&yd)[NTOK][4],
    const unsigned int* lds_w, const float* lds_bq, const float* lds_bp,
    const float* lds_pb, int quad, int nl, size_t b, int isbf,
    void* __restrict__ out) {
  // ===================== layer 0 =====================
  unsigned int od[2][NTOK][2];
#pragma unroll
  for (int s = 0; s < 2; ++s) {  // head-slot pass: tiles {s,2+s,4+s} = q,k,v of head quad+4s
    const half8_t waq = ldsfrag(lds_w, (s) * 16 + nl, quad);
    const half8_t wak = ldsfrag(lds_w, (2 + s) * 16 + nl, quad);
    const half8_t wav = ldsfrag(lds_w, (4 + s) * 16 + nl, quad);
    const f32x4 bq = *(const f32x4*)(lds_bq + (s) * 16 + quad * 4);
    const f32x4 bk = *(const f32x4*)(lds_bq + (2 + s) * 16 + quad * 4);
    const f32x4 bv = *(const f32x4*)(lds_bq + (4 + s) * 16 + quad * 4);
    unsigned int qd[NTOK][2], kd[NTOK][2];
    f32x4 vv[NTOK];
#pragma unroll
    for (int t = 0; t < NTOK; ++t) {
      const half8_t yb = mk8(yd[t]);
      const f32x4 aq = __builtin_amdgcn_mfma_f32_16x16x32_f16(waq, yb, bq, 0, 0, 0);
      qd[t][0] = pk(aq[0], aq[1]); qd[t][1] = pk(aq[2], aq[3]);
      const f32x4 ak = __builtin_amdgcn_mfma_f32_16x16x32_f16(wak, yb, bk, 0, 0, 0);
      kd[t][0] = pk(ak[0], ak[1]); kd[t][1] = pk(ak[2], ak[3]);
      vv[t] = __builtin_amdgcn_mfma_f32_16x16x32_f16(wav, yb, bv, 0, 0, 0);
    }
    attn_head<NTOK>(qd, kd, vv, lds_pb + (quad + 4 * s) * 40, od[s]);
  }

  {  // proj + residual; o natively pi layout -> direct B-operand; C natively pi
    half8_t wp[2]; f32x4 bp[2];
#pragma unroll
    for (int tile = 0; tile < 2; ++tile) {
      wp[tile] = ldsfrag(lds_w, 192 + tile * 16 + nl, quad);
      bp[tile] = *(const f32x4*)(lds_bp + tile * 16 + quad * 4);
    }
#pragma unroll
    for (int t = 0; t < NTOK; ++t) {
      unsigned int bfr[4] = {od[0][t][0], od[0][t][1], od[1][t][0], od[1][t][1]};
      const half8_t ob = mk8(bfr);
      f32x4 p0 = __builtin_amdgcn_mfma_f32_16x16x32_f16(wp[0], ob, bp[0], 0, 0, 0);
      f32x4 p1 = __builtin_amdgcn_mfma_f32_16x16x32_f16(wp[1], ob, bp[1], 0, 0, 0);
      yd[t][0] = h2u(u2h(yd[t][0]) + u2h(pk(p0[0], p0[1])));
      yd[t][1] = h2u(u2h(yd[t][1]) + u2h(pk(p0[2], p0[3])));
      yd[t][2] = h2u(u2h(yd[t][2]) + u2h(pk(p1[0], p1[1])));
      yd[t][3] = h2u(u2h(yd[t][3]) + u2h(pk(p1[2], p1[3])));
    }
  }

  // ===================== layer 1 (token-0 output only) =====================
  unsigned int o1[2][1][2];
#pragma unroll
  for (int s = 0; s < 2; ++s) {
    const half8_t waq = ldsfrag(lds_w, 96 + (s) * 16 + nl, quad);
    const half8_t wak = ldsfrag(lds_w, 96 + (2 + s) * 16 + nl, quad);
    const half8_t wav = ldsfrag(lds_w, 96 + (4 + s) * 16 + nl, quad);
    const f32x4 bq = *(const f32x4*)(lds_bq + 96 + (s) * 16 + quad * 4);
    const f32x4 bk = *(const f32x4*)(lds_bq + 96 + (2 + s) * 16 + quad * 4);
    const f32x4 bv = *(const f32x4*)(lds_bq + 96 + (4 + s) * 16 + quad * 4);
    unsigned int qd[1][2], kd[NTOK][2];
    f32x4 vv[NTOK];
    {  // q: token 0 only
      const f32x4 aq = __builtin_amdgcn_mfma_f32_16x16x32_f16(waq, mk8(yd[0]), bq, 0, 0, 0);
      qd[0][0] = pk(aq[0], aq[1]); qd[0][1] = pk(aq[2], aq[3]);
    }
#pragma unroll
    for (int t = 0; t < NTOK; ++t) {
      const half8_t yb = mk8(yd[t]);
      const f32x4 ak = __builtin_amdgcn_mfma_f32_16x16x32_f16(wak, yb, bk, 0, 0, 0);
      kd[t][0] = pk(ak[0], ak[1]); kd[t][1] = pk(ak[2], ak[3]);
      vv[t] = __builtin_amdgcn_mfma_f32_16x16x32_f16(wav, yb, bv, 0, 0, 0);
    }
    attn_head<1>(qd, kd, vv, lds_pb + (8 + quad + 4 * s) * 40, o1[s]);
  }

  {
    half8_t wp[2]; f32x4 bp[2];
#pragma unroll
    for (int tile = 0; tile < 2; ++tile) {
      wp[tile] = ldsfrag(lds_w, 192 + 32 + tile * 16 + nl, quad);
      bp[tile] = *(const f32x4*)(lds_bp + 32 + tile * 16 + quad * 4);
    }
    unsigned int bfr[4] = {o1[0][0][0], o1[0][0][1], o1[1][0][0], o1[1][0][1]};
    const half8_t ob = mk8(bfr);
    f32x4 p0 = __builtin_amdgcn_mfma_f32_16x16x32_f16(wp[0], ob, bp[0], 0, 0, 0);
    f32x4 p1 = __builtin_amdgcn_mfma_f32_16x16x32_f16(wp[1], ob, bp[1], 0, 0, 0);

    // f32-exact final residual; lane q holds channels {4q..4q+3, 4q+16..4q+19}
    const half2_t y0 = u2h(yd[0][0]), y1 = u2h(yd[0][1]);
    const half2_t y2 = u2h(yd[0][2]), y3 = u2h(yd[0][3]);
    float f[8] = {(float)y0.x + p0[0], (float)y0.y + p0[1],
                  (float)y1.x + p0[2], (float)y1.y + p0[3],
                  (float)y2.x + p1[0], (float)y2.y + p1[1],
                  (float)y3.x + p1[2], (float)y3.y + p1[3]};
    if (isbf) {
      unsigned short* ob16 = (unsigned short*)out + b * 32;
      *(uint2*)(ob16 + quad * 4) = make_uint2(f2bfpair(f[0], f[1]), f2bfpair(f[2], f[3]));
      *(uint2*)(ob16 + quad * 4 + 16) = make_uint2(f2bfpair(f[4], f[5]), f2bfpair(f[6], f[7]));
    } else {
      float* of = (float*)out + b * 32;
      *(float4*)(of + quad * 4) = make_float4(f[0], f[1], f[2], f[3]);
      *(float4*)(of + quad * 4 + 16) = make_float4(f[4], f[5], f[6], f[7]);
    }
  }
}

// ---------------- main kernel: 1 wave = 2 groups of 16 rows, pipelined ----------------
__global__ __launch_bounds__(256, 4) void vit_kernel(
    const void* __restrict__ x, const void* __restrict__ token,
    const unsigned int* __restrict__ wqkv, const unsigned int* __restrict__ wproj,
    const float* __restrict__ bqkv, const float* __restrict__ bproj,
    const float* __restrict__ pb, const int* __restrict__ flag,
    void* __restrict__ out) {
  // LDS parameter cache: ~24KB/block (6 blocks/CU cap = 24 waves).
  __shared__ unsigned int lds_w[256 * 20];  // rows 0..191 qkv, 192..255 proj; 80B rows
  __shared__ float lds_bq[192];
  __shared__ float lds_bp[64];
  __shared__ float lds_pb[640];

  const int tid = threadIdx.x;
  const int wave = tid >> 6, lane = tid & 63;
  const int quad = lane >> 4, nl = lane & 15;
  const int rowoff = wave * 16 + nl;
  const size_t b0 = (size_t)blockIdx.x * 128 + rowoff;
  const size_t b1 = b0 + 64;
  const int isbf = *flag;  // wave-uniform

  // ---- issue BOTH groups' raw x loads up front (g1 stays in flight through
  // g0's whole compute; group compute bodies contain no vmcnt reads).
  float4 rf0[8], rf1[8];
  uint2 rb0[8], rb1[8];
  if (isbf) {
    const unsigned short* xb0 = (const unsigned short*)x + b0 * 128;
    const unsigned short* xb1 = (const unsigned short*)x + b1 * 128;
#pragma unroll
    for (int t = 1; t < NTOK; ++t) {
      const unsigned short* base = xb0 + (t - 1) * 32;
      rb0[2 * (t - 1)] = *(const uint2*)(base + quad * 4);
      rb0[2 * (t - 1) + 1] = *(const uint2*)(base + quad * 4 + 16);
    }
#pragma unroll
    for (int t = 1; t < NTOK; ++t) {
      const unsigned short* base = xb1 + (t - 1) * 32;
      rb1[2 * (t - 1)] = *(const uint2*)(base + quad * 4);
      rb1[2 * (t - 1) + 1] = *(const uint2*)(base + quad * 4 + 16);
    }
  } else {
    const float* xb0 = (const float*)x + b0 * 128;
    const float* xb1 = (const float*)x + b1 * 128;
#pragma unroll
    for (int t = 1; t < NTOK; ++t) {
      const float* base = xb0 + (t - 1) * 32;
      rf0[2 * (t - 1)] = *(const float4*)(base + quad * 4);
      rf0[2 * (t - 1) + 1] = *(const float4*)(base + quad * 4 + 16);
    }
#pragma unroll
    for (int t = 1; t < NTOK; ++t) {
      const float* base = xb1 + (t - 1) * 32;
      rf1[2 * (t - 1)] = *(const float4*)(base + quad * 4);
      rf1[2 * (t - 1) + 1] = *(const float4*)(base + quad * 4 + 16);
    }
  }

  // ---- stage parameters into LDS (global ws is small + L2-hot)
  {
    const uint4* sq = (const uint4*)wqkv;  // 768 uint4
#pragma unroll
    for (int k = 0; k < 3; ++k) {
      const int i = tid + k * 256;
      *(uint4*)(lds_w + (i >> 2) * 20 + (i & 3) * 4) = sq[i];
    }
    const uint4* sp = (const uint4*)wproj;  // 256 uint4
    *(uint4*)(lds_w + (192 + (tid >> 2)) * 20 + (tid & 3) * 4) = sp[tid];
    if (tid < 192) lds_bq[tid] = bqkv[tid];
    if (tid < 64) lds_bp[tid] = bproj[tid];
    {
      const uint4* spb = (const uint4*)pb;  // 160 uint4
      if (tid < 160) *(uint4*)((float*)lds_pb + tid * 4) = spb[tid];
    }
  }

  // ---- token -> fp16 pi layout (shared by both groups)
  unsigned int tokd[4];
  if (isbf) {
    const unsigned short* tk = (const unsigned short*)token;
    const uint2 t0 = *(const uint2*)(tk + quad * 4);
    const uint2 t1 = *(const uint2*)(tk + quad * 4 + 16);
    tokd[0] = h2u(bfpair2h2(t0.x)); tokd[1] = h2u(bfpair2h2(t0.y));
    tokd[2] = h2u(bfpair2h2(t1.x)); tokd[3] = h2u(bfpair2h2(t1.y));
  } else {
    const float* tk = (const float*)token;
    const float4 a0 = *(const float4*)(tk + quad * 4);
    const float4 a1 = *(const float4*)(tk + quad * 4 + 16);
    tokd[0] = pk(a0.x, a0.y); tokd[1] = pk(a0.z, a0.w);
    tokd[2] = pk(a1.x, a1.y); tokd[3] = pk(a1.z, a1.w);
  }
  __syncthreads();

  // ---- group 0: convert (waits g0 loads only; g1 outstanding) + compute
  unsigned int yd0[NTOK][4];
  yd0[0][0] = tokd[0]; yd0[0][1] = tokd[1]; yd0[0][2] = tokd[2]; yd0[0][3] = tokd[3];
  if (isbf) {
#pragma unroll
    for (int t = 1; t < NTOK; ++t) {
      yd0[t][0] = h2u(bfpair2h2(rb0[2 * (t - 1)].x));
      yd0[t][1] = h2u(bfpair2h2(rb0[2 * (t - 1)].y));
      yd0[t][2] = h2u(bfpair2h2(rb0[2 * (t - 1) + 1].x));
      yd0[t][3] = h2u(bfpair2h2(rb0[2 * (t - 1) + 1].y));
    }
  } else {
#pragma unroll
    for (int t = 1; t < NTOK; ++t) {
      yd0[t][0] = pk(rf0[2 * (t - 1)].x, rf0[2 * (t - 1)].y);
      yd0[t][1] = pk(rf0[2 * (t - 1)].z, rf0[2 * (t - 1)].w);
      yd0[t][2] = pk(rf0[2 * (t - 1) + 1].x, rf0[2 * (t - 1) + 1].y);
      yd0[t][3] = pk(rf0[2 * (t - 1) + 1].z, rf0[2 * (t - 1) + 1].w);
    }
  }
  vit_compute_store(yd0, lds_w, lds_bq, lds_bp, lds_pb, quad, nl, b0, isbf, out);

  // ---- group 1: loads have had g0's whole compute to land
  unsigned int yd1[NTOK][4];
  yd1[0][0] = tokd[0]; yd1[0][1] = tokd[1]; yd1[0][2] = tokd[2]; yd1[0][3] = tokd[3];
  if (isbf) {
#pragma unroll
    for (int t = 1; t < NTOK; ++t) {
      yd1[t][0] = h2u(bfpair2h2(rb1[2 * (t - 1)].x));
      yd1[t][1] = h2u(bfpair2h2(rb1[2 * (t - 1)].y));
      yd1[t][2] = h2u(bfpair2h2(rb1[2 * (t - 1) + 1].x));
      yd1[t][3] = h2u(bfpair2h2(rb1[2 * (t - 1) + 1].y));
    }
  } else {
#pragma unroll
    for (int t = 1; t < NTOK; ++t) {
      yd1[t][0] = pk(rf1[2 * (t - 1)].x, rf1[2 * (t - 1)].y);
      yd1[t][1] = pk(rf1[2 * (t - 1)].z, rf1[2 * (t - 1)].w);
      yd1[t][2] = pk(rf1[2 * (t - 1) + 1].x, rf1[2 * (t - 1) + 1].y);
      yd1[t][3] = pk(rf1[2 * (t - 1) + 1].z, rf1[2 * (t - 1) + 1].w);
    }
  }
  vit_compute_store(yd1, lds_w, lds_bq, lds_bp, lds_pb, quad, nl, b1, isbf, out);
}

extern "C" void kernel_launch(void* const* d_in, const int* in_sizes, int n_in,
                              void* d_out, int out_size, void* d_ws, size_t ws_size,
                              hipStream_t stream) {
  const void* x      = d_in[0];
  const void* token  = d_in[1];
  const void* qkv_w  = d_in[2];
  const void* qkv_b  = d_in[3];
  const void* proj_w = d_in[4];
  const void* proj_b = d_in[5];
  const void* pos_b  = d_in[6];

  char* ws = (char*)d_ws;
  unsigned int* wqkv  = (unsigned int*)(ws + 0);
  unsigned int* wproj = (unsigned int*)(ws + 12288);
  float* bqkv  = (float*)(ws + 16384);
  float* bproj = (float*)(ws + 17152);
  float* pb    = (float*)(ws + 17408);   // 640 f32, [l][h][n][8] padded
  int*   flag  = (int*)(ws + 19968);

  prep_kernel<<<1, 256, 0, stream>>>(x, qkv_w, qkv_b, proj_w, proj_b, pos_b,
                                     wqkv, wproj, bqkv, bproj, pb, flag);

  const int nrows = in_sizes[0] / 128;  // 262144 batch rows
  const int grid = nrows / 128;         // 2048 blocks; 2 groups of 64 rows each
  vit_kernel<<<grid, 256, 0, stream>>>(x, token, wqkv, wproj, bqkv, bproj, pb, flag, d_out);
}

// Round 6
// 355.412 us; speedup vs baseline: 1.1792x; 1.0070x over previous
//
#include <hip/hip_runtime.h>
#include <hip/hip_bf16.h>

// nnvit_82042465288319 on MI355X (gfx950). B=262144 rows; y[5][32]; 2 layers
// (H=8, HD=4); out = y[0] after layer 1. Inputs f32 (dtype probe keeps a bf16
// path for safety).
//
// Round 9 design (2-deep pipeline, register-budgeted to NOT spill):
//  - R7/R8 spilled (~940B scratch/thread): rf0+rf1 (64 VGPR) + rb0/rb1 (32,
//    live across the isbf join) + compute set (~60) > 128 cap. Fixes:
//    (a) launch_bounds(256,3) -> cap ~168, 3 blocks/CU;
//    (b) dtype paths fully disjoint (separate if/else pipelines) so rf/rb
//        never co-allocate;
//    (c) V packed to fp16 again (R5 proved f32-V was perf-neutral): -10 VGPR.
//    f32-path peak ~= rf1(32)+yd(20)+compute(~70) ~= 125 < 168.
//  - Pipeline: issue BOTH groups' x loads up front; single vmcnt drain at
//    the param-staging barrier; g0 compute has ZERO vmcnt reads (params in
//    LDS on lgkm path); g1 converts with no wait. One latency exposure per
//    128 rows instead of per 64 (Little's law: R1's 1.28TB/s ~ 2KB/CU
//    outstanding at 900cy -> exposure-bound).
//  - bf16 safety path: non-pipelined (correctness only).
//  - Keeps: pi-permuted channels (zero shuffles), padded pb rows, log2e
//    softmax (no max-shift), LDS params.

#define NTOK 5

typedef decltype(__builtin_amdgcn_cvt_pkrtz(0.0f, 0.0f)) half2_t;
using half8_t = __attribute__((ext_vector_type(8))) _Float16;
using f32x4 = __attribute__((ext_vector_type(4))) float;
using f32x2 = __attribute__((ext_vector_type(2))) float;

union H2 { half2_t h; unsigned int u; };
union H8 { half8_t h; uint4 u4; unsigned int u[4]; };

__device__ __forceinline__ half2_t u2h(unsigned int x) { H2 c; c.u = x; return c.h; }
__device__ __forceinline__ unsigned int h2u(half2_t h) { H2 c; c.h = h; return c.u; }
__device__ __forceinline__ unsigned int pk(float a, float b) {
  return h2u(__builtin_amdgcn_cvt_pkrtz(a, b));
}
__device__ __forceinline__ float bf2f(unsigned short u) {
  union { unsigned int u; float f; } c; c.u = ((unsigned int)u) << 16; return c.f;
}
__device__ __forceinline__ half2_t bfpair2h2(unsigned int u) {
  union { unsigned int u; float f; } lo, hi;
  lo.u = u << 16;
  hi.u = u & 0xffff0000u;
  return __builtin_amdgcn_cvt_pkrtz(lo.f, hi.f);  // exact: bf16 fits fp16 range here
}
// round-to-nearest-even f32 pair -> packed bf16 pair
__device__ __forceinline__ unsigned int f2bfpair(float a, float b) {
  unsigned int ua = __float_as_uint(a), ub = __float_as_uint(b);
  ua = (ua + 0x7fffu + ((ua >> 16) & 1u)) >> 16;
  ub = (ub + 0x7fffu + ((ub >> 16) & 1u)) & 0xffff0000u;
  return ua | ub;
}

// dtype probe: low 16 bits of each word form a normal-band bf16 exponent iff bf16
__device__ __forceinline__ int detect_bf16(const unsigned int* __restrict__ p) {
  int cnt = 0;
#pragma unroll
  for (int i = 0; i < 64; ++i) {
    unsigned int e = (p[i] >> 7) & 0xffu;
    cnt += (e >= 96u && e <= 150u) ? 1 : 0;
  }
  return (cnt >= 40) ? 1 : 0;
}

// channel permutation: pi(8q+j) = 4q + (j&3) + (j>=4 ? 16 : 0)
__device__ __forceinline__ int permch(int pos) {
  return 4 * (pos >> 3) + (pos & 3) + ((pos & 4) ? 16 : 0);
}

// ---------------- prep ----------------
// ws: wqkv u32[3072]@0 | wproj u32[1024]@12288 | bqkv f32[192]@16384
//     bproj f32[64]@17152 | pb f32[640]@17408 (layout [l][h][n][8], *log2e)
//     | flag int@19968
__global__ void prep_kernel(const void* __restrict__ xraw,
                            const void* __restrict__ qkv_w, const void* __restrict__ qkv_b,
                            const void* __restrict__ proj_w, const void* __restrict__ proj_b,
                            const void* __restrict__ pos_b,
                            unsigned int* __restrict__ wqkv, unsigned int* __restrict__ wproj,
                            float* __restrict__ bqkv, float* __restrict__ bproj,
                            float* __restrict__ pb, int* __restrict__ flag) {
  const int t = threadIdx.x;  // single block of 256
  const int isbf = detect_bf16((const unsigned int*)xraw);
  if (t == 0) *flag = isbf;
  const float LOG2E = 1.44269504f;
  if (isbf) {
    const unsigned short* qw = (const unsigned short*)qkv_w;
    const unsigned short* qb = (const unsigned short*)qkv_b;
    const unsigned short* pw = (const unsigned short*)proj_w;
    const unsigned short* pbb = (const unsigned short*)proj_b;
    const unsigned short* pp = (const unsigned short*)pos_b;
    for (int i = t; i < 3072; i += 256) {
      const int row = i >> 4, cp = (i & 15) * 2;
      wqkv[i] = h2u(__builtin_amdgcn_cvt_pkrtz(bf2f(qw[row * 32 + permch(cp)]),
                                               bf2f(qw[row * 32 + permch(cp + 1)])));
    }
    for (int i = t; i < 1024; i += 256) {
      const int row = i >> 4, cp = (i & 15) * 2;
      wproj[i] = h2u(__builtin_amdgcn_cvt_pkrtz(bf2f(pw[row * 32 + permch(cp)]),
                                                bf2f(pw[row * 32 + permch(cp + 1)])));
    }
    for (int i = t; i < 192; i += 256) bqkv[i] = bf2f(qb[i]);
    for (int i = t; i < 64; i += 256) bproj[i] = bf2f(pbb[i]);
    for (int i = t; i < 640; i += 256) {
      const int m = i & 7, r = i >> 3;       // r = lh*5 + n, lh in [0,16)
      const int n = r % 5, lh = r / 5;
      pb[i] = (m < 5) ? bf2f(pp[lh * 25 + n * 5 + m]) * LOG2E : 0.0f;
    }
  } else {
    const float* qw = (const float*)qkv_w;
    const float* qb = (const float*)qkv_b;
    const float* pw = (const float*)proj_w;
    const float* pbb = (const float*)proj_b;
    const float* pp = (const float*)pos_b;
    for (int i = t; i < 3072; i += 256) {
      const int row = i >> 4, cp = (i & 15) * 2;
      wqkv[i] = h2u(__builtin_amdgcn_cvt_pkrtz(qw[row * 32 + permch(cp)],
                                               qw[row * 32 + permch(cp + 1)]));
    }
    for (int i = t; i < 1024; i += 256) {
      const int row = i >> 4, cp = (i & 15) * 2;
      wproj[i] = h2u(__builtin_amdgcn_cvt_pkrtz(pw[row * 32 + permch(cp)],
                                                pw[row * 32 + permch(cp + 1)]));
    }
    for (int i = t; i < 192; i += 256) bqkv[i] = qb[i];
    for (int i = t; i < 64; i += 256) bproj[i] = pbb[i];
    for (int i = t; i < 640; i += 256) {
      const int m = i & 7, r = i >> 3;
      const int n = r % 5, lh = r / 5;
      pb[i] = (m < 5) ? pp[lh * 25 + n * 5 + m] * LOG2E : 0.0f;
    }
  }
}

__device__ __forceinline__ half8_t mk8(const unsigned int (&d)[4]) {
  H8 c; c.u[0] = d[0]; c.u[1] = d[1]; c.u[2] = d[2]; c.u[3] = d[3]; return c.h;
}

// LDS weight-frag read: rows padded to 80B (20 u32). lane holds
// W[row][quad*8 .. quad*8+7] (8 fp16 = 16B). Stride 20 words -> 2-way bank
// aliasing across 16 nl lanes (free per m136).
__device__ __forceinline__ half8_t ldsfrag(const unsigned int* lw, int row, int quad) {
  H8 c; c.u4 = *(const uint4*)(lw + row * 20 + quad * 4); return c.h;
}

// per-lane attention for one head. q/k/v all packed fp16 dword pairs (v
// packed to save 10 VGPR in the pipelined peak region; perf-neutral per R5).
// pbh points at [n][8]-padded, log2e-prescaled rows (in LDS). No max-shift.
template <int NR>
__device__ __forceinline__ void attn_head(const unsigned int (&qd)[NR][2],
                                          const unsigned int (&kd)[NTOK][2],
                                          const unsigned int (&vd)[NTOK][2],
                                          const float* pbh,
                                          unsigned int (&od)[NR][2]) {
  float vf[NTOK][4];
#pragma unroll
  for (int m = 0; m < NTOK; ++m) {
    const half2_t v0 = u2h(vd[m][0]), v1 = u2h(vd[m][1]);
    vf[m][0] = (float)v0.x; vf[m][1] = (float)v0.y;
    vf[m][2] = (float)v1.x; vf[m][3] = (float)v1.y;
  }
#pragma unroll
  for (int n = 0; n < NR; ++n) {
    const f32x4 pbv = *(const f32x4*)(pbh + n * 8);
    const float pb4 = pbh[n * 8 + 4];
    const float pbm[NTOK] = {pbv[0], pbv[1], pbv[2], pbv[3], pb4};
    const half2_t q0 = u2h(qd[n][0]), q1 = u2h(qd[n][1]);
    float e[NTOK];
#pragma unroll
    for (int m = 0; m < NTOK; ++m) {
      float d = __builtin_amdgcn_fdot2(q0, u2h(kd[m][0]), 0.0f, false);
      d = __builtin_amdgcn_fdot2(q1, u2h(kd[m][1]), d, false);
      // scale = HD^-0.5 * log2(e) = 0.5 * 1.44269504
      e[m] = __builtin_amdgcn_exp2f(fmaf(d, 0.72134752f, pbm[m]));
    }
    const float ssum = ((e[0] + e[1]) + (e[2] + e[3])) + e[4];
    const float r = __builtin_amdgcn_rcpf(ssum);
    float o0 = 0.f, o1 = 0.f, o2 = 0.f, o3 = 0.f;
#pragma unroll
    for (int m = 0; m < NTOK; ++m) {
      o0 = fmaf(e[m], vf[m][0], o0); o1 = fmaf(e[m], vf[m][1], o1);
      o2 = fmaf(e[m], vf[m][2], o2); o3 = fmaf(e[m], vf[m][3], o3);
    }
    od[n][0] = pk(o0 * r, o1 * r);
    od[n][1] = pk(o2 * r, o3 * r);
  }
}

// Full 2-layer pipeline + store for one 16-row group (per wave). Pure
// LDS/VALU/MFMA - no vmcnt reads inside (keeps other group's x loads in
// flight). yd is consumed/clobbered.
template <int ISBF>
__device__ __forceinline__ void vit_compute_store(
    unsigned int (&yd)[NTOK][4],
    const unsigned int* lds_w, const float* lds_bq, const float* lds_bp,
    const float* lds_pb, int quad, int nl, size_t b,
    void* __restrict__ out) {
  // ===================== layer 0 =====================
  unsigned int od[2][NTOK][2];
#pragma unroll
  for (int s = 0; s < 2; ++s) {  // head-slot pass: tiles {s,2+s,4+s} = q,k,v of head quad+4s
    const half8_t waq = ldsfrag(lds_w, (s) * 16 + nl, quad);
    const half8_t wak = ldsfrag(lds_w, (2 + s) * 16 + nl, quad);
    const half8_t wav = ldsfrag(lds_w, (4 + s) * 16 + nl, quad);
    const f32x4 bq = *(const f32x4*)(lds_bq + (s) * 16 + quad * 4);
    const f32x4 bk = *(const f32x4*)(lds_bq + (2 + s) * 16 + quad * 4);
    const f32x4 bv = *(const f32x4*)(lds_bq + (4 + s) * 16 + quad * 4);
    unsigned int qd[NTOK][2], kd[NTOK][2], vd[NTOK][2];
#pragma unroll
    for (int t = 0; t < NTOK; ++t) {
      const half8_t yb = mk8(yd[t]);
      const f32x4 aq = __builtin_amdgcn_mfma_f32_16x16x32_f16(waq, yb, bq, 0, 0, 0);
      qd[t][0] = pk(aq[0], aq[1]); qd[t][1] = pk(aq[2], aq[3]);
      const f32x4 ak = __builtin_amdgcn_mfma_f32_16x16x32_f16(wak, yb, bk, 0, 0, 0);
      kd[t][0] = pk(ak[0], ak[1]); kd[t][1] = pk(ak[2], ak[3]);
      const f32x4 av = __builtin_amdgcn_mfma_f32_16x16x32_f16(wav, yb, bv, 0, 0, 0);
      vd[t][0] = pk(av[0], av[1]); vd[t][1] = pk(av[2], av[3]);
    }
    attn_head<NTOK>(qd, kd, vd, lds_pb + (quad + 4 * s) * 40, od[s]);
  }

  {  // proj + residual; o natively pi layout -> direct B-operand; C natively pi
    half8_t wp[2]; f32x4 bp[2];
#pragma unroll
    for (int tile = 0; tile < 2; ++tile) {
      wp[tile] = ldsfrag(lds_w, 192 + tile * 16 + nl, quad);
      bp[tile] = *(const f32x4*)(lds_bp + tile * 16 + quad * 4);
    }
#pragma unroll
    for (int t = 0; t < NTOK; ++t) {
      unsigned int bfr[4] = {od[0][t][0], od[0][t][1], od[1][t][0], od[1][t][1]};
      const half8_t ob = mk8(bfr);
      f32x4 p0 = __builtin_amdgcn_mfma_f32_16x16x32_f16(wp[0], ob, bp[0], 0, 0, 0);
      f32x4 p1 = __builtin_amdgcn_mfma_f32_16x16x32_f16(wp[1], ob, bp[1], 0, 0, 0);
      yd[t][0] = h2u(u2h(yd[t][0]) + u2h(pk(p0[0], p0[1])));
      yd[t][1] = h2u(u2h(yd[t][1]) + u2h(pk(p0[2], p0[3])));
      yd[t][2] = h2u(u2h(yd[t][2]) + u2h(pk(p1[0], p1[1])));
      yd[t][3] = h2u(u2h(yd[t][3]) + u2h(pk(p1[2], p1[3])));
    }
  }

  // ===================== layer 1 (token-0 output only) =====================
  unsigned int o1[2][1][2];
#pragma unroll
  for (int s = 0; s < 2; ++s) {
    const half8_t waq = ldsfrag(lds_w, 96 + (s) * 16 + nl, quad);
    const half8_t wak = ldsfrag(lds_w, 96 + (2 + s) * 16 + nl, quad);
    const half8_t wav = ldsfrag(lds_w, 96 + (4 + s) * 16 + nl, quad);
    const f32x4 bq = *(const f32x4*)(lds_bq + 96 + (s) * 16 + quad * 4);
    const f32x4 bk = *(const f32x4*)(lds_bq + 96 + (2 + s) * 16 + quad * 4);
    const f32x4 bv = *(const f32x4*)(lds_bq + 96 + (4 + s) * 16 + quad * 4);
    unsigned int qd[1][2], kd[NTOK][2], vd[NTOK][2];
    {  // q: token 0 only
      const f32x4 aq = __builtin_amdgcn_mfma_f32_16x16x32_f16(waq, mk8(yd[0]), bq, 0, 0, 0);
      qd[0][0] = pk(aq[0], aq[1]); qd[0][1] = pk(aq[2], aq[3]);
    }
#pragma unroll
    for (int t = 0; t < NTOK; ++t) {
      const half8_t yb = mk8(yd[t]);
      const f32x4 ak = __builtin_amdgcn_mfma_f32_16x16x32_f16(wak, yb, bk, 0, 0, 0);
      kd[t][0] = pk(ak[0], ak[1]); kd[t][1] = pk(ak[2], ak[3]);
      const f32x4 av = __builtin_amdgcn_mfma_f32_16x16x32_f16(wav, yb, bv, 0, 0, 0);
      vd[t][0] = pk(av[0], av[1]); vd[t][1] = pk(av[2], av[3]);
    }
    attn_head<1>(qd, kd, vd, lds_pb + (8 + quad + 4 * s) * 40, o1[s]);
  }

  {
    half8_t wp[2]; f32x4 bp[2];
#pragma unroll
    for (int tile = 0; tile < 2; ++tile) {
      wp[tile] = ldsfrag(lds_w, 192 + 32 + tile * 16 + nl, quad);
      bp[tile] = *(const f32x4*)(lds_bp + 32 + tile * 16 + quad * 4);
    }
    unsigned int bfr[4] = {o1[0][0][0], o1[0][0][1], o1[1][0][0], o1[1][0][1]};
    const half8_t ob = mk8(bfr);
    f32x4 p0 = __builtin_amdgcn_mfma_f32_16x16x32_f16(wp[0], ob, bp[0], 0, 0, 0);
    f32x4 p1 = __builtin_amdgcn_mfma_f32_16x16x32_f16(wp[1], ob, bp[1], 0, 0, 0);

    // f32-exact final residual; lane q holds channels {4q..4q+3, 4q+16..4q+19}
    const half2_t y0 = u2h(yd[0][0]), y1 = u2h(yd[0][1]);
    const half2_t y2 = u2h(yd[0][2]), y3 = u2h(yd[0][3]);
    float f[8] = {(float)y0.x + p0[0], (float)y0.y + p0[1],
                  (float)y1.x + p0[2], (float)y1.y + p0[3],
                  (float)y2.x + p1[0], (float)y2.y + p1[1],
                  (float)y3.x + p1[2], (float)y3.y + p1[3]};
    if (ISBF) {
      unsigned short* ob16 = (unsigned short*)out + b * 32;
      *(uint2*)(ob16 + quad * 4) = make_uint2(f2bfpair(f[0], f[1]), f2bfpair(f[2], f[3]));
      *(uint2*)(ob16 + quad * 4 + 16) = make_uint2(f2bfpair(f[4], f[5]), f2bfpair(f[6], f[7]));
    } else {
      float* of = (float*)out + b * 32;
      *(float4*)(of + quad * 4) = make_float4(f[0], f[1], f[2], f[3]);
      *(float4*)(of + quad * 4 + 16) = make_float4(f[4], f[5], f[6], f[7]);
    }
  }
}

// ---------------- main kernel: 1 wave = 2 groups of 16 rows, pipelined ----------------
__global__ __launch_bounds__(256, 3) void vit_kernel(
    const void* __restrict__ x, const void* __restrict__ token,
    const unsigned int* __restrict__ wqkv, const unsigned int* __restrict__ wproj,
    const float* __restrict__ bqkv, const float* __restrict__ bproj,
    const float* __restrict__ pb, const int* __restrict__ flag,
    void* __restrict__ out) {
  // LDS parameter cache: ~24KB/block (3 blocks/CU at launch_bounds cap).
  __shared__ unsigned int lds_w[256 * 20];  // rows 0..191 qkv, 192..255 proj; 80B rows
  __shared__ float lds_bq[192];
  __shared__ float lds_bp[64];
  __shared__ float lds_pb[640];

  const int tid = threadIdx.x;
  const int wave = tid >> 6, lane = tid & 63;
  const int quad = lane >> 4, nl = lane & 15;
  const int rowoff = wave * 16 + nl;
  const size_t b0 = (size_t)blockIdx.x * 128 + rowoff;
  const size_t b1 = b0 + 64;
  const int isbf = *flag;  // wave-uniform

  // ---- f32 fast path: issue BOTH groups' x loads up front. bf16 path: g0 only.
  float4 rf0[8], rf1[8];
  uint2 rb0[8];
  if (!isbf) {
    const float* xb0 = (const float*)x + b0 * 128;
#pragma unroll
    for (int t = 1; t < NTOK; ++t) {
      const float* base = xb0 + (t - 1) * 32;
      rf0[2 * (t - 1)] = *(const float4*)(base + quad * 4);
      rf0[2 * (t - 1) + 1] = *(const float4*)(base + quad * 4 + 16);
    }
    const float* xb1 = (const float*)x + b1 * 128;
#pragma unroll
    for (int t = 1; t < NTOK; ++t) {
      const float* base = xb1 + (t - 1) * 32;
      rf1[2 * (t - 1)] = *(const float4*)(base + quad * 4);
      rf1[2 * (t - 1) + 1] = *(const float4*)(base + quad * 4 + 16);
    }
  } else {
    const unsigned short* xb0 = (const unsigned short*)x + b0 * 128;
#pragma unroll
    for (int t = 1; t < NTOK; ++t) {
      const unsigned short* base = xb0 + (t - 1) * 32;
      rb0[2 * (t - 1)] = *(const uint2*)(base + quad * 4);
      rb0[2 * (t - 1) + 1] = *(const uint2*)(base + quad * 4 + 16);
    }
  }

  // ---- stage parameters into LDS (global ws is small + L2-hot)
  {
    const uint4* sq = (const uint4*)wqkv;  // 768 uint4
#pragma unroll
    for (int k = 0; k < 3; ++k) {
      const int i = tid + k * 256;
      *(uint4*)(lds_w + (i >> 2) * 20 + (i & 3) * 4) = sq[i];
    }
    const uint4* sp = (const uint4*)wproj;  // 256 uint4
    *(uint4*)(lds_w + (192 + (tid >> 2)) * 20 + (tid & 3) * 4) = sp[tid];
    if (tid < 192) lds_bq[tid] = bqkv[tid];
    if (tid < 64) lds_bp[tid] = bproj[tid];
    {
      const uint4* spb = (const uint4*)pb;  // 160 uint4
      if (tid < 160) *(uint4*)((float*)lds_pb + tid * 4) = spb[tid];
    }
  }

  // ---- token -> fp16 pi layout (shared by both groups)
  unsigned int tokd[4];
  if (isbf) {
    const unsigned short* tk = (const unsigned short*)token;
    const uint2 t0 = *(const uint2*)(tk + quad * 4);
    const uint2 t1 = *(const uint2*)(tk + quad * 4 + 16);
    tokd[0] = h2u(bfpair2h2(t0.x)); tokd[1] = h2u(bfpair2h2(t0.y));
    tokd[2] = h2u(bfpair2h2(t1.x)); tokd[3] = h2u(bfpair2h2(t1.y));
  } else {
    const float* tk = (const float*)token;
    const float4 a0 = *(const float4*)(tk + quad * 4);
    const float4 a1 = *(const float4*)(tk + quad * 4 + 16);
    tokd[0] = pk(a0.x, a0.y); tokd[1] = pk(a0.z, a0.w);
    tokd[2] = pk(a1.x, a1.y); tokd[3] = pk(a1.z, a1.w);
  }
  __syncthreads();

  if (!isbf) {
    // ---- g0: convert + compute (zero vmcnt reads inside compute)
    unsigned int yd0[NTOK][4];
    yd0[0][0] = tokd[0]; yd0[0][1] = tokd[1]; yd0[0][2] = tokd[2]; yd0[0][3] = tokd[3];
#pragma unroll
    for (int t = 1; t < NTOK; ++t) {
      yd0[t][0] = pk(rf0[2 * (t - 1)].x, rf0[2 * (t - 1)].y);
      yd0[t][1] = pk(rf0[2 * (t - 1)].z, rf0[2 * (t - 1)].w);
      yd0[t][2] = pk(rf0[2 * (t - 1) + 1].x, rf0[2 * (t - 1) + 1].y);
      yd0[t][3] = pk(rf0[2 * (t - 1) + 1].z, rf0[2 * (t - 1) + 1].w);
    }
    vit_compute_store<0>(yd0, lds_w, lds_bq, lds_bp, lds_pb, quad, nl, b0, out);

    // ---- g1: data long since landed; no new latency exposure
    unsigned int yd1[NTOK][4];
    yd1[0][0] = tokd[0]; yd1[0][1] = tokd[1]; yd1[0][2] = tokd[2]; yd1[0][3] = tokd[3];
#pragma unroll
    for (int t = 1; t < NTOK; ++t) {
      yd1[t][0] = pk(rf1[2 * (t - 1)].x, rf1[2 * (t - 1)].y);
      yd1[t][1] = pk(rf1[2 * (t - 1)].z, rf1[2 * (t - 1)].w);
      yd1[t][2] = pk(rf1[2 * (t - 1) + 1].x, rf1[2 * (t - 1) + 1].y);
      yd1[t][3] = pk(rf1[2 * (t - 1) + 1].z, rf1[2 * (t - 1) + 1].w);
    }
    vit_compute_store<0>(yd1, lds_w, lds_bq, lds_bp, lds_pb, quad, nl, b1, out);
  } else {
    // ---- bf16 safety path: non-pipelined (correctness; real input is f32)
    unsigned int yd0[NTOK][4];
    yd0[0][0] = tokd[0]; yd0[0][1] = tokd[1]; yd0[0][2] = tokd[2]; yd0[0][3] = tokd[3];
#pragma unroll
    for (int t = 1; t < NTOK; ++t) {
      yd0[t][0] = h2u(bfpair2h2(rb0[2 * (t - 1)].x));
      yd0[t][1] = h2u(bfpair2h2(rb0[2 * (t - 1)].y));
      yd0[t][2] = h2u(bfpair2h2(rb0[2 * (t - 1) + 1].x));
      yd0[t][3] = h2u(bfpair2h2(rb0[2 * (t - 1) + 1].y));
    }
    vit_compute_store<1>(yd0, lds_w, lds_bq, lds_bp, lds_pb, quad, nl, b0, out);

    unsigned int rb1[8];
    const unsigned short* xb1 = (const unsigned short*)x + b1 * 128;
#pragma unroll
    for (int t = 1; t < NTOK; ++t) {
      const unsigned short* base = xb1 + (t - 1) * 32;
      const uint2 u0 = *(const uint2*)(base + quad * 4);
      const uint2 u1 = *(const uint2*)(base + quad * 4 + 16);
      rb1[2 * (t - 1)] = u0.x; rb1[2 * (t - 1) + 1] = u0.y;
      rb1[2 * (t - 1) + 4] = u1.x;  // unused slots avoided below
      rb1[2 * (t - 1) + 1] = u0.y;
      unsigned int yy0 = h2u(bfpair2h2(u0.x)), yy1 = h2u(bfpair2h2(u0.y));
      unsigned int yy2 = h2u(bfpair2h2(u1.x)), yy3 = h2u(bfpair2h2(u1.y));
      rb1[2 * (t - 1)] = yy0; rb1[2 * (t - 1) + 1] = yy1;
      // store converted directly into yd1 below via rb1 reuse
      rb1[2 * (t - 1)] = yy0;
      (void)yy2; (void)yy3;
      // fall through: we rebuild yd1 from fresh loads below for clarity
    }
    unsigned int yd1[NTOK][4];
    yd1[0][0] = tokd[0]; yd1[0][1] = tokd[1]; yd1[0][2] = tokd[2]; yd1[0][3] = tokd[3];
#pragma unroll
    for (int t = 1; t < NTOK; ++t) {
      const unsigned short* base = xb1 + (t - 1) * 32;
      const uint2 u0 = *(const uint2*)(base + quad * 4);
      const uint2 u1 = *(const uint2*)(base + quad * 4 + 16);
      yd1[t][0] = h2u(bfpair2h2(u0.x));
      yd1[t][1] = h2u(bfpair2h2(u0.y));
      yd1[t][2] = h2u(bfpair2h2(u1.x));
      yd1[t][3] = h2u(bfpair2h2(u1.y));
    }
    vit_compute_store<1>(yd1, lds_w, lds_bq, lds_bp, lds_pb, quad, nl, b1, out);
  }
}

extern "C" void kernel_launch(void* const* d_in, const int* in_sizes, int n_in,
                              void* d_out, int out_size, void* d_ws, size_t ws_size,
                              hipStream_t stream) {
  const void* x      = d_in[0];
  const void* token  = d_in[1];
  const void* qkv_w  = d_in[2];
  const void* qkv_b  = d_in[3];
  const void* proj_w = d_in[4];
  const void* proj_b = d_in[5];
  const void* pos_b  = d_in[6];

  char* ws = (char*)d_ws;
  unsigned int* wqkv  = (unsigned int*)(ws + 0);
  unsigned int* wproj = (unsigned int*)(ws + 12288);
  float* bqkv  = (float*)(ws + 16384);
  float* bproj = (float*)(ws + 17152);
  float* pb    = (float*)(ws + 17408);   // 640 f32, [l][h][n][8] padded
  int*   flag  = (int*)(ws + 19968);

  prep_kernel<<<1, 256, 0, stream>>>(x, qkv_w, qkv_b, proj_w, proj_b, pos_b,
                                     wqkv, wproj, bqkv, bproj, pb, flag);

  const int nrows = in_sizes[0] / 128;  // 262144 batch rows
  const int grid = nrows / 128;         // 2048 blocks; 2 groups of 64 rows each
  vit_kernel<<<grid, 256, 0, stream>>>(x, token, wqkv, wproj, bqkv, bproj, pb, flag, d_out);
}

// Round 7
// 229.713 us; speedup vs baseline: 1.8245x; 1.5472x over previous
//
#include <hip/hip_runtime.h>
#include <hip/hip_bf16.h>

// nnvit_82042465288319 on MI355X (gfx950). B=262144 rows; y[5][32]; 2 layers
// (H=8, HD=4); out = y[0] after layer 1. Inputs f32 (dtype probe keeps a bf16
// path for safety).
//
// Round 10 design (LDS-staged x pipeline via global_load_lds; spill-immune):
//  - R7/R8/R9 all spilled trying to hold raw x in VGPRs across compute.
//    R6's spill traffic proved HBM sustains 3.5+ TB/s when enough requests
//    are outstanding; clean kernel only reaches 1.3 (exposure-bound).
//  - Fix: pipeline through LDS. 512 blocks (all co-resident, 2/CU at 56.8KB
//    LDS), each loops 8 groups x 64 rows. Per group: ds_read x -> yd regs ->
//    barrier -> issue next group's 32KB via global_load_lds (NO VGPRs) ->
//    compute+store (zero vmcnt reads: params in LDS) -> vmcnt(0)+barrier.
//  - global_load_lds dest is linear (base+lane*16, m104), so bank-balance
//    via pre-swizzled GLOBAL source (m173): row r col c lives at LDS
//    r*512 + (c ^ ((r&7)<<4)); readback uses same XOR. b128 readback then
//    hits all 8 bank-slots evenly (optimal).
//  - Loop-carried regs: tokd[4] + scalars only (R7's spill cause removed).
//  - bf16 probe path: non-pipelined direct loads (correctness only).
//  - Keeps: pi-permuted channels (zero shuffles), padded pb rows, log2e
//    softmax (no max-shift), LDS params (80B-padded weight rows).

#define NTOK 5
#define GROUPS 8

typedef decltype(__builtin_amdgcn_cvt_pkrtz(0.0f, 0.0f)) half2_t;
using half8_t = __attribute__((ext_vector_type(8))) _Float16;
using f32x4 = __attribute__((ext_vector_type(4))) float;

union H2 { half2_t h; unsigned int u; };
union H8 { half8_t h; uint4 u4; unsigned int u[4]; };

__device__ __forceinline__ half2_t u2h(unsigned int x) { H2 c; c.u = x; return c.h; }
__device__ __forceinline__ unsigned int h2u(half2_t h) { H2 c; c.h = h; return c.u; }
__device__ __forceinline__ unsigned int pk(float a, float b) {
  return h2u(__builtin_amdgcn_cvt_pkrtz(a, b));
}
__device__ __forceinline__ float bf2f(unsigned short u) {
  union { unsigned int u; float f; } c; c.u = ((unsigned int)u) << 16; return c.f;
}
__device__ __forceinline__ half2_t bfpair2h2(unsigned int u) {
  union { unsigned int u; float f; } lo, hi;
  lo.u = u << 16;
  hi.u = u & 0xffff0000u;
  return __builtin_amdgcn_cvt_pkrtz(lo.f, hi.f);  // exact: bf16 fits fp16 range here
}
// round-to-nearest-even f32 pair -> packed bf16 pair
__device__ __forceinline__ unsigned int f2bfpair(float a, float b) {
  unsigned int ua = __float_as_uint(a), ub = __float_as_uint(b);
  ua = (ua + 0x7fffu + ((ua >> 16) & 1u)) >> 16;
  ub = (ub + 0x7fffu + ((ub >> 16) & 1u)) & 0xffff0000u;
  return ua | ub;
}

// async 16B global -> LDS (no VGPR round-trip). size must be literal 16.
__device__ __forceinline__ void stage16(const void* g, void* l) {
  __builtin_amdgcn_global_load_lds(
      (const __attribute__((address_space(1))) unsigned int*)g,
      (__attribute__((address_space(3))) unsigned int*)l, 16, 0, 0);
}

// dtype probe: low 16 bits of each word form a normal-band bf16 exponent iff bf16
__device__ __forceinline__ int detect_bf16(const unsigned int* __restrict__ p) {
  int cnt = 0;
#pragma unroll
  for (int i = 0; i < 64; ++i) {
    unsigned int e = (p[i] >> 7) & 0xffu;
    cnt += (e >= 96u && e <= 150u) ? 1 : 0;
  }
  return (cnt >= 40) ? 1 : 0;
}

// channel permutation: pi(8q+j) = 4q + (j&3) + (j>=4 ? 16 : 0)
__device__ __forceinline__ int permch(int pos) {
  return 4 * (pos >> 3) + (pos & 3) + ((pos & 4) ? 16 : 0);
}

// ---------------- prep ----------------
// ws: wqkv u32[3072]@0 | wproj u32[1024]@12288 | bqkv f32[192]@16384
//     bproj f32[64]@17152 | pb f32[640]@17408 (layout [l][h][n][8], *log2e)
//     | flag int@19968
__global__ void prep_kernel(const void* __restrict__ xraw,
                            const void* __restrict__ qkv_w, const void* __restrict__ qkv_b,
                            const void* __restrict__ proj_w, const void* __restrict__ proj_b,
                            const void* __restrict__ pos_b,
                            unsigned int* __restrict__ wqkv, unsigned int* __restrict__ wproj,
                            float* __restrict__ bqkv, float* __restrict__ bproj,
                            float* __restrict__ pb, int* __restrict__ flag) {
  const int t = threadIdx.x;  // single block of 256
  const int isbf = detect_bf16((const unsigned int*)xraw);
  if (t == 0) *flag = isbf;
  const float LOG2E = 1.44269504f;
  if (isbf) {
    const unsigned short* qw = (const unsigned short*)qkv_w;
    const unsigned short* qb = (const unsigned short*)qkv_b;
    const unsigned short* pw = (const unsigned short*)proj_w;
    const unsigned short* pbb = (const unsigned short*)proj_b;
    const unsigned short* pp = (const unsigned short*)pos_b;
    for (int i = t; i < 3072; i += 256) {
      const int row = i >> 4, cp = (i & 15) * 2;
      wqkv[i] = h2u(__builtin_amdgcn_cvt_pkrtz(bf2f(qw[row * 32 + permch(cp)]),
                                               bf2f(qw[row * 32 + permch(cp + 1)])));
    }
    for (int i = t; i < 1024; i += 256) {
      const int row = i >> 4, cp = (i & 15) * 2;
      wproj[i] = h2u(__builtin_amdgcn_cvt_pkrtz(bf2f(pw[row * 32 + permch(cp)]),
                                                bf2f(pw[row * 32 + permch(cp + 1)])));
    }
    for (int i = t; i < 192; i += 256) bqkv[i] = bf2f(qb[i]);
    for (int i = t; i < 64; i += 256) bproj[i] = bf2f(pbb[i]);
    for (int i = t; i < 640; i += 256) {
      const int m = i & 7, r = i >> 3;       // r = lh*5 + n, lh in [0,16)
      const int n = r % 5, lh = r / 5;
      pb[i] = (m < 5) ? bf2f(pp[lh * 25 + n * 5 + m]) * LOG2E : 0.0f;
    }
  } else {
    const float* qw = (const float*)qkv_w;
    const float* qb = (const float*)qkv_b;
    const float* pw = (const float*)proj_w;
    const float* pbb = (const float*)proj_b;
    const float* pp = (const float*)pos_b;
    for (int i = t; i < 3072; i += 256) {
      const int row = i >> 4, cp = (i & 15) * 2;
      wqkv[i] = h2u(__builtin_amdgcn_cvt_pkrtz(qw[row * 32 + permch(cp)],
                                               qw[row * 32 + permch(cp + 1)]));
    }
    for (int i = t; i < 1024; i += 256) {
      const int row = i >> 4, cp = (i & 15) * 2;
      wproj[i] = h2u(__builtin_amdgcn_cvt_pkrtz(pw[row * 32 + permch(cp)],
                                                pw[row * 32 + permch(cp + 1)]));
    }
    for (int i = t; i < 192; i += 256) bqkv[i] = qb[i];
    for (int i = t; i < 64; i += 256) bproj[i] = pbb[i];
    for (int i = t; i < 640; i += 256) {
      const int m = i & 7, r = i >> 3;
      const int n = r % 5, lh = r / 5;
      pb[i] = (m < 5) ? pp[lh * 25 + n * 5 + m] * LOG2E : 0.0f;
    }
  }
}

__device__ __forceinline__ half8_t mk8(const unsigned int (&d)[4]) {
  H8 c; c.u[0] = d[0]; c.u[1] = d[1]; c.u[2] = d[2]; c.u[3] = d[3]; return c.h;
}

// LDS weight-frag read: rows padded to 80B (20 u32); stride 80B lands the 16
// nl-lanes evenly on the 8 bank-slots (conflict-free b128).
__device__ __forceinline__ half8_t ldsfrag(const unsigned int* lw, int row, int quad) {
  H8 c; c.u4 = *(const uint4*)(lw + row * 20 + quad * 4); return c.h;
}

// per-lane attention for one head. q/k/v packed fp16 dword pairs.
// pbh points at [n][8]-padded, log2e-prescaled rows (in LDS). No max-shift.
template <int NR>
__device__ __forceinline__ void attn_head(const unsigned int (&qd)[NR][2],
                                          const unsigned int (&kd)[NTOK][2],
                                          const unsigned int (&vd)[NTOK][2],
                                          const float* pbh,
                                          unsigned int (&od)[NR][2]) {
  float vf[NTOK][4];
#pragma unroll
  for (int m = 0; m < NTOK; ++m) {
    const half2_t v0 = u2h(vd[m][0]), v1 = u2h(vd[m][1]);
    vf[m][0] = (float)v0.x; vf[m][1] = (float)v0.y;
    vf[m][2] = (float)v1.x; vf[m][3] = (float)v1.y;
  }
#pragma unroll
  for (int n = 0; n < NR; ++n) {
    const f32x4 pbv = *(const f32x4*)(pbh + n * 8);
    const float pb4 = pbh[n * 8 + 4];
    const float pbm[NTOK] = {pbv[0], pbv[1], pbv[2], pbv[3], pb4};
    const half2_t q0 = u2h(qd[n][0]), q1 = u2h(qd[n][1]);
    float e[NTOK];
#pragma unroll
    for (int m = 0; m < NTOK; ++m) {
      float d = __builtin_amdgcn_fdot2(q0, u2h(kd[m][0]), 0.0f, false);
      d = __builtin_amdgcn_fdot2(q1, u2h(kd[m][1]), d, false);
      // scale = HD^-0.5 * log2(e) = 0.5 * 1.44269504
      e[m] = __builtin_amdgcn_exp2f(fmaf(d, 0.72134752f, pbm[m]));
    }
    const float ssum = ((e[0] + e[1]) + (e[2] + e[3])) + e[4];
    const float r = __builtin_amdgcn_rcpf(ssum);
    float o0 = 0.f, o1 = 0.f, o2 = 0.f, o3 = 0.f;
#pragma unroll
    for (int m = 0; m < NTOK; ++m) {
      o0 = fmaf(e[m], vf[m][0], o0); o1 = fmaf(e[m], vf[m][1], o1);
      o2 = fmaf(e[m], vf[m][2], o2); o3 = fmaf(e[m], vf[m][3], o3);
    }
    od[n][0] = pk(o0 * r, o1 * r);
    od[n][1] = pk(o2 * r, o3 * r);
  }
}

// Full 2-layer pipeline + store for one 16-row group (per wave). Pure
// LDS/VALU/MFMA - no vmcnt reads inside. yd is consumed/clobbered.
template <int ISBF>
__device__ __forceinline__ void vit_compute_store(
    unsigned int (&yd)[NTOK][4],
    const unsigned int* lds_w, const float* lds_bq, const float* lds_bp,
    const float* lds_pb, int quad, int nl, size_t b,
    void* __restrict__ out) {
  // ===================== layer 0 =====================
  unsigned int od[2][NTOK][2];
#pragma unroll
  for (int s = 0; s < 2; ++s) {  // head-slot pass: tiles {s,2+s,4+s} = q,k,v of head quad+4s
    const half8_t waq = ldsfrag(lds_w, (s) * 16 + nl, quad);
    const half8_t wak = ldsfrag(lds_w, (2 + s) * 16 + nl, quad);
    const half8_t wav = ldsfrag(lds_w, (4 + s) * 16 + nl, quad);
    const f32x4 bq = *(const f32x4*)(lds_bq + (s) * 16 + quad * 4);
    const f32x4 bk = *(const f32x4*)(lds_bq + (2 + s) * 16 + quad * 4);
    const f32x4 bv = *(const f32x4*)(lds_bq + (4 + s) * 16 + quad * 4);
    unsigned int qd[NTOK][2], kd[NTOK][2], vd[NTOK][2];
#pragma unroll
    for (int t = 0; t < NTOK; ++t) {
      const half8_t yb = mk8(yd[t]);
      const f32x4 aq = __builtin_amdgcn_mfma_f32_16x16x32_f16(waq, yb, bq, 0, 0, 0);
      qd[t][0] = pk(aq[0], aq[1]); qd[t][1] = pk(aq[2], aq[3]);
      const f32x4 ak = __builtin_amdgcn_mfma_f32_16x16x32_f16(wak, yb, bk, 0, 0, 0);
      kd[t][0] = pk(ak[0], ak[1]); kd[t][1] = pk(ak[2], ak[3]);
      const f32x4 av = __builtin_amdgcn_mfma_f32_16x16x32_f16(wav, yb, bv, 0, 0, 0);
      vd[t][0] = pk(av[0], av[1]); vd[t][1] = pk(av[2], av[3]);
    }
    attn_head<NTOK>(qd, kd, vd, lds_pb + (quad + 4 * s) * 40, od[s]);
  }

  {  // proj + residual; o natively pi layout -> direct B-operand; C natively pi
    half8_t wp[2]; f32x4 bp[2];
#pragma unroll
    for (int tile = 0; tile < 2; ++tile) {
      wp[tile] = ldsfrag(lds_w, 192 + tile * 16 + nl, quad);
      bp[tile] = *(const f32x4*)(lds_bp + tile * 16 + quad * 4);
    }
#pragma unroll
    for (int t = 0; t < NTOK; ++t) {
      unsigned int bfr[4] = {od[0][t][0], od[0][t][1], od[1][t][0], od[1][t][1]};
      const half8_t ob = mk8(bfr);
      f32x4 p0 = __builtin_amdgcn_mfma_f32_16x16x32_f16(wp[0], ob, bp[0], 0, 0, 0);
      f32x4 p1 = __builtin_amdgcn_mfma_f32_16x16x32_f16(wp[1], ob, bp[1], 0, 0, 0);
      yd[t][0] = h2u(u2h(yd[t][0]) + u2h(pk(p0[0], p0[1])));
      yd[t][1] = h2u(u2h(yd[t][1]) + u2h(pk(p0[2], p0[3])));
      yd[t][2] = h2u(u2h(yd[t][2]) + u2h(pk(p1[0], p1[1])));
      yd[t][3] = h2u(u2h(yd[t][3]) + u2h(pk(p1[2], p1[3])));
    }
  }

  // ===================== layer 1 (token-0 output only) =====================
  unsigned int o1[2][1][2];
#pragma unroll
  for (int s = 0; s < 2; ++s) {
    const half8_t waq = ldsfrag(lds_w, 96 + (s) * 16 + nl, quad);
    const half8_t wak = ldsfrag(lds_w, 96 + (2 + s) * 16 + nl, quad);
    const half8_t wav = ldsfrag(lds_w, 96 + (4 + s) * 16 + nl, quad);
    const f32x4 bq = *(const f32x4*)(lds_bq + 96 + (s) * 16 + quad * 4);
    const f32x4 bk = *(const f32x4*)(lds_bq + 96 + (2 + s) * 16 + quad * 4);
    const f32x4 bv = *(const f32x4*)(lds_bq + 96 + (4 + s) * 16 + quad * 4);
    unsigned int qd[1][2], kd[NTOK][2], vd[NTOK][2];
    {  // q: token 0 only
      const f32x4 aq = __builtin_amdgcn_mfma_f32_16x16x32_f16(waq, mk8(yd[0]), bq, 0, 0, 0);
      qd[0][0] = pk(aq[0], aq[1]); qd[0][1] = pk(aq[2], aq[3]);
    }
#pragma unroll
    for (int t = 0; t < NTOK; ++t) {
      const half8_t yb = mk8(yd[t]);
      const f32x4 ak = __builtin_amdgcn_mfma_f32_16x16x32_f16(wak, yb, bk, 0, 0, 0);
      kd[t][0] = pk(ak[0], ak[1]); kd[t][1] = pk(ak[2], ak[3]);
      const f32x4 av = __builtin_amdgcn_mfma_f32_16x16x32_f16(wav, yb, bv, 0, 0, 0);
      vd[t][0] = pk(av[0], av[1]); vd[t][1] = pk(av[2], av[3]);
    }
    attn_head<1>(qd, kd, vd, lds_pb + (8 + quad + 4 * s) * 40, o1[s]);
  }

  {
    half8_t wp[2]; f32x4 bp[2];
#pragma unroll
    for (int tile = 0; tile < 2; ++tile) {
      wp[tile] = ldsfrag(lds_w, 192 + 32 + tile * 16 + nl, quad);
      bp[tile] = *(const f32x4*)(lds_bp + 32 + tile * 16 + quad * 4);
    }
    unsigned int bfr[4] = {o1[0][0][0], o1[0][0][1], o1[1][0][0], o1[1][0][1]};
    const half8_t ob = mk8(bfr);
    f32x4 p0 = __builtin_amdgcn_mfma_f32_16x16x32_f16(wp[0], ob, bp[0], 0, 0, 0);
    f32x4 p1 = __builtin_amdgcn_mfma_f32_16x16x32_f16(wp[1], ob, bp[1], 0, 0, 0);

    // f32-exact final residual; lane q holds channels {4q..4q+3, 4q+16..4q+19}
    const half2_t y0 = u2h(yd[0][0]), y1 = u2h(yd[0][1]);
    const half2_t y2 = u2h(yd[0][2]), y3 = u2h(yd[0][3]);
    float f[8] = {(float)y0.x + p0[0], (float)y0.y + p0[1],
                  (float)y1.x + p0[2], (float)y1.y + p0[3],
                  (float)y2.x + p1[0], (float)y2.y + p1[1],
                  (float)y3.x + p1[2], (float)y3.y + p1[3]};
    if (ISBF) {
      unsigned short* ob16 = (unsigned short*)out + b * 32;
      *(uint2*)(ob16 + quad * 4) = make_uint2(f2bfpair(f[0], f[1]), f2bfpair(f[2], f[3]));
      *(uint2*)(ob16 + quad * 4 + 16) = make_uint2(f2bfpair(f[4], f[5]), f2bfpair(f[6], f[7]));
    } else {
      float* of = (float*)out + b * 32;
      *(float4*)(of + quad * 4) = make_float4(f[0], f[1], f[2], f[3]);
      *(float4*)(of + quad * 4 + 16) = make_float4(f[4], f[5], f[6], f[7]);
    }
  }
}

// ---------------- main kernel: 512 resident blocks, 8 groups x 64 rows each ----------------
__global__ __launch_bounds__(256, 2) void vit_kernel(
    const void* __restrict__ x, const void* __restrict__ token,
    const unsigned int* __restrict__ wqkv, const unsigned int* __restrict__ wproj,
    const float* __restrict__ bqkv, const float* __restrict__ bproj,
    const float* __restrict__ pb, const int* __restrict__ flag,
    void* __restrict__ out) {
  __shared__ unsigned int lds_w[256 * 20];  // 20KB: rows 0..191 qkv, 192..255 proj (80B rows)
  __shared__ float lds_bq[192];
  __shared__ float lds_bp[64];
  __shared__ float lds_pb[640];
  __shared__ float lds_x[8192];             // 32KB: one 64-row f32 group, XOR-swizzled

  const int tid = threadIdx.x;
  const int wave = tid >> 6, lane = tid & 63;
  const int quad = lane >> 4, nl = lane & 15;
  const int rowoff = wave * 16 + nl;        // 0..63 within group
  const size_t blkrow = (size_t)blockIdx.x * (64 * GROUPS);
  const int isbf = *flag;  // grid-uniform

  // ---- stage group 0 x into LDS (f32 path; zero VGPR) ----
  if (!isbf) {
    const char* gb = (const char*)x + blkrow * 512;
#pragma unroll
    for (int k = 0; k < 8; ++k) {
      const int L = k * 4096 + wave * 1024 + lane * 16;
      const int row = L >> 9, colS = L & 511;
      const int src = row * 512 + (colS ^ ((row & 7) << 4));
      stage16(gb + src, (char*)lds_x + k * 4096 + wave * 1024);
    }
  }

  // ---- stage parameters into LDS ----
  {
    const uint4* sq = (const uint4*)wqkv;  // 768 uint4
#pragma unroll
    for (int k = 0; k < 3; ++k) {
      const int i = tid + k * 256;
      *(uint4*)(lds_w + (i >> 2) * 20 + (i & 3) * 4) = sq[i];
    }
    const uint4* sp = (const uint4*)wproj;  // 256 uint4
    *(uint4*)(lds_w + (192 + (tid >> 2)) * 20 + (tid & 3) * 4) = sp[tid];
    if (tid < 192) lds_bq[tid] = bqkv[tid];
    if (tid < 64) lds_bp[tid] = bproj[tid];
    const uint4* spb = (const uint4*)pb;  // 160 uint4
    if (tid < 160) *(uint4*)((float*)lds_pb + tid * 4) = spb[tid];
  }

  // ---- token -> fp16 pi layout (loop-carried: 4 VGPR only) ----
  unsigned int tokd[4];
  if (isbf) {
    const unsigned short* tk = (const unsigned short*)token;
    const uint2 t0 = *(const uint2*)(tk + quad * 4);
    const uint2 t1 = *(const uint2*)(tk + quad * 4 + 16);
    tokd[0] = h2u(bfpair2h2(t0.x)); tokd[1] = h2u(bfpair2h2(t0.y));
    tokd[2] = h2u(bfpair2h2(t1.x)); tokd[3] = h2u(bfpair2h2(t1.y));
  } else {
    const float* tk = (const float*)token;
    const float4 a0 = *(const float4*)(tk + quad * 4);
    const float4 a1 = *(const float4*)(tk + quad * 4 + 16);
    tokd[0] = pk(a0.x, a0.y); tokd[1] = pk(a0.z, a0.w);
    tokd[2] = pk(a1.x, a1.y); tokd[3] = pk(a1.z, a1.w);
  }

  if (!isbf) {
    // compiler drains vmcnt+lgkmcnt before s_barrier -> group-0 x and params ready
    __syncthreads();

    const int sw = (rowoff & 7) << 4;
    const char* lx = (const char*)lds_x;
#pragma unroll 1
    for (int g = 0; g < GROUPS; ++g) {
      // ---- readback + convert: x[rowoff] from swizzled LDS -> yd (fp16 pi) ----
      unsigned int yd[NTOK][4];
      yd[0][0] = tokd[0]; yd[0][1] = tokd[1]; yd[0][2] = tokd[2]; yd[0][3] = tokd[3];
#pragma unroll
      for (int t = 1; t < NTOK; ++t) {
        const int colA = (t - 1) * 128 + quad * 16;
        const float4 u0 = *(const float4*)(lx + rowoff * 512 + (colA ^ sw));
        const float4 u1 = *(const float4*)(lx + rowoff * 512 + ((colA + 64) ^ sw));
        yd[t][0] = pk(u0.x, u0.y); yd[t][1] = pk(u0.z, u0.w);
        yd[t][2] = pk(u1.x, u1.y); yd[t][3] = pk(u1.z, u1.w);
      }
      __syncthreads();  // all waves done reading lds_x; safe to overwrite

      // ---- issue next group's staging (lands under compute; no VGPRs) ----
      if (g + 1 < GROUPS) {
        const char* gb = (const char*)x + (blkrow + (size_t)(g + 1) * 64) * 512;
#pragma unroll
        for (int k = 0; k < 8; ++k) {
          const int L = k * 4096 + wave * 1024 + lane * 16;
          const int row = L >> 9, colS = L & 511;
          const int src = row * 512 + (colS ^ ((row & 7) << 4));
          stage16(gb + src, (char*)lds_x + k * 4096 + wave * 1024);
        }
      }

      // ---- full 2-layer compute + store (zero vmcnt reads inside) ----
      vit_compute_store<0>(yd, lds_w, lds_bq, lds_bp, lds_pb, quad, nl,
                           blkrow + (size_t)g * 64 + rowoff, out);

      // ---- ensure staging complete before next readback ----
      asm volatile("s_waitcnt vmcnt(0)" ::: "memory");
      __syncthreads();
    }
  } else {
    // ---- bf16 safety path: non-pipelined (correctness; real input is f32) ----
    __syncthreads();
#pragma unroll 1
    for (int g = 0; g < GROUPS; ++g) {
      const size_t b = blkrow + (size_t)g * 64 + rowoff;
      unsigned int yd[NTOK][4];
      yd[0][0] = tokd[0]; yd[0][1] = tokd[1]; yd[0][2] = tokd[2]; yd[0][3] = tokd[3];
      const unsigned short* xb = (const unsigned short*)x + b * 128;
#pragma unroll
      for (int t = 1; t < NTOK; ++t) {
        const unsigned short* base = xb + (t - 1) * 32;
        const uint2 u0 = *(const uint2*)(base + quad * 4);
        const uint2 u1 = *(const uint2*)(base + quad * 4 + 16);
        yd[t][0] = h2u(bfpair2h2(u0.x)); yd[t][1] = h2u(bfpair2h2(u0.y));
        yd[t][2] = h2u(bfpair2h2(u1.x)); yd[t][3] = h2u(bfpair2h2(u1.y));
      }
      vit_compute_store<1>(yd, lds_w, lds_bq, lds_bp, lds_pb, quad, nl, b, out);
    }
  }
}

extern "C" void kernel_launch(void* const* d_in, const int* in_sizes, int n_in,
                              void* d_out, int out_size, void* d_ws, size_t ws_size,
                              hipStream_t stream) {
  const void* x      = d_in[0];
  const void* token  = d_in[1];
  const void* qkv_w  = d_in[2];
  const void* qkv_b  = d_in[3];
  const void* proj_w = d_in[4];
  const void* proj_b = d_in[5];
  const void* pos_b  = d_in[6];

  char* ws = (char*)d_ws;
  unsigned int* wqkv  = (unsigned int*)(ws + 0);
  unsigned int* wproj = (unsigned int*)(ws + 12288);
  float* bqkv  = (float*)(ws + 16384);
  float* bproj = (float*)(ws + 17152);
  float* pb    = (float*)(ws + 17408);   // 640 f32, [l][h][n][8] padded
  int*   flag  = (int*)(ws + 19968);

  prep_kernel<<<1, 256, 0, stream>>>(x, qkv_w, qkv_b, proj_w, proj_b, pos_b,
                                     wqkv, wproj, bqkv, bproj, pb, flag);

  const int nrows = in_sizes[0] / 128;      // 262144 batch rows
  const int grid = nrows / (64 * GROUPS);   // 512 blocks (2/CU resident, 56.8KB LDS)
  vit_kernel<<<grid, 256, 0, stream>>>(x, token, wqkv, wproj, bqkv, bproj, pb, flag, d_out);
}